// Round 11
// baseline (862.752 us; speedup 1.0000x reference)
//
#include <hip/hip_runtime.h>
#include <math.h>

typedef __attribute__((ext_vector_type(8))) short short8;
typedef __attribute__((ext_vector_type(4))) float f32x4;
typedef __attribute__((ext_vector_type(4))) float f4;
typedef __attribute__((ext_vector_type(4))) unsigned short us4;
typedef unsigned short u16;

#define Bn 32
#define Ln 128
#define Dn 512
#define LATn 256
#define Vn 50257
#define VPAD 50304
#define DFn 2048
#define Hn 8
#define HDn 64

#define GLD(src, dst) __builtin_amdgcn_global_load_lds( \
    (const __attribute__((address_space(1))) unsigned int*)(src), \
    (__attribute__((address_space(3))) unsigned int*)(dst), 16, 0, 0)

__device__ __forceinline__ u16 f2bf(float f) {
  union { float f; unsigned u; } v; v.f = f;
  unsigned r = 0x7FFFu + ((v.u >> 16) & 1u);
  return (u16)((v.u + r) >> 16);
}
__device__ __forceinline__ float bf2f(u16 u) {
  union { unsigned u; float f; } v; v.u = ((unsigned)u) << 16;
  return v.f;
}

// ---------------- all weights f32 -> bf16, one kernel (contiguous dst arena) -
__global__ __launch_bounds__(256)
void k_cvt_all(const float* __restrict__ s0, const float* __restrict__ s1,
               const float* __restrict__ s2, const float* __restrict__ s3,
               const float* __restrict__ s4, us4* __restrict__ dst) {
  const int C0 = 786432;    // qkv  4*1536*512/4
  const int C1 = 1048576;   // +out 4*512*512/4
  const int C2 = 2097152;   // +ff1 4*2048*512/4
  const int C3 = 3145728;   // +ff2
  const int C4 = 9584640;   // +op (VPAD*512/4)
  const int OPN4 = 6432896; // op real Vn*512/4
  int i = blockIdx.x * blockDim.x + threadIdx.x;
  int stride = gridDim.x * blockDim.x;
  for (; i < C4; i += stride) {
    const f4* src; int off; bool valid = true;
    if (i < C0)      { src = (const f4*)s0; off = i; }
    else if (i < C1) { src = (const f4*)s1; off = i - C0; }
    else if (i < C2) { src = (const f4*)s2; off = i - C1; }
    else if (i < C3) { src = (const f4*)s3; off = i - C2; }
    else             { src = (const f4*)s4; off = i - C3; valid = off < OPN4; }
    us4 o;
    if (valid) {
      f4 v = src[off];
      o[0] = f2bf(v[0]); o[1] = f2bf(v[1]); o[2] = f2bf(v[2]); o[3] = f2bf(v[3]);
    } else { o[0] = 0; o[1] = 0; o[2] = 0; o[3] = 0; }
    dst[i] = o;
  }
}

// ---------------- latent_proj: mem = LN(GELU(z @ lp_w.T + lp_b)) -------------
__global__ __launch_bounds__(256)
void k_latent_mem(const float* __restrict__ z, const float* __restrict__ lp_w,
                  const float* __restrict__ lp_b, const float* __restrict__ g,
                  const float* __restrict__ be, float* __restrict__ mem) {
  __shared__ float zs[LATn];
  __shared__ float red[16];
  int b = blockIdx.x, t = threadIdx.x;
  zs[t] = z[b * LATn + t];
  __syncthreads();
  float h[2];
  #pragma unroll
  for (int j = 0; j < 2; j++) {
    int oj = t + j * 256;
    const float* w = lp_w + (size_t)oj * LATn;
    float s0 = 0, s1 = 0, s2 = 0, s3 = 0;
    for (int k = 0; k < LATn; k += 4) {
      s0 += zs[k] * w[k]; s1 += zs[k+1] * w[k+1];
      s2 += zs[k+2] * w[k+2]; s3 += zs[k+3] * w[k+3];
    }
    float x = s0 + s1 + s2 + s3 + lp_b[oj];
    h[j] = 0.5f * x * (1.0f + erff(x * 0.70710678118654752f));
  }
  float sum = h[0] + h[1], sq = h[0]*h[0] + h[1]*h[1];
  for (int off = 32; off; off >>= 1) {
    sum += __shfl_down(sum, off, 64);
    sq  += __shfl_down(sq,  off, 64);
  }
  int lane = t & 63, wid = t >> 6;
  if (!lane) { red[wid] = sum; red[8 + wid] = sq; }
  __syncthreads();
  float ts = red[0] + red[1] + red[2] + red[3];
  float tq = red[8] + red[9] + red[10] + red[11];
  float mu = ts * (1.0f / Dn);
  float var = tq * (1.0f / Dn) - mu * mu;
  float rstd = rsqrtf(fmaxf(var, 0.0f) + 1e-5f);
  #pragma unroll
  for (int j = 0; j < 2; j++) {
    int oj = t + j * 256;
    mem[b * Dn + oj] = (h[j] - mu) * rstd * g[oj] + be[oj];
  }
}

// ------------- cross-attention precompute (Lk=1 => softmax==1 => o = v) ------
__global__ __launch_bounds__(256)
void k_ca(const float* __restrict__ mem, const float* __restrict__ ca_qkv_w,
          const float* __restrict__ ca_qkv_b, const float* __restrict__ ca_out_w,
          const float* __restrict__ ca_out_b, float* __restrict__ ca_add) {
  int blk = blockIdx.x;
  int i = blk >> 5, b = blk & 31, t = threadIdx.x;
  __shared__ float ms[Dn];
  __shared__ float vs[Dn];
  ms[t] = mem[b * Dn + t];
  ms[t + 256] = mem[b * Dn + t + 256];
  __syncthreads();
  const float* wv = ca_qkv_w + ((size_t)i * 1536 + 1024) * Dn;
  const float* bv = ca_qkv_b + i * 1536 + 1024;
  for (int j = t; j < Dn; j += 256) {
    const float* w = wv + (size_t)j * Dn;
    float s0 = 0, s1 = 0, s2 = 0, s3 = 0;
    for (int k = 0; k < Dn; k += 4) {
      s0 += ms[k]*w[k]; s1 += ms[k+1]*w[k+1]; s2 += ms[k+2]*w[k+2]; s3 += ms[k+3]*w[k+3];
    }
    vs[j] = s0 + s1 + s2 + s3 + bv[j];
  }
  __syncthreads();
  const float* wo = ca_out_w + (size_t)i * Dn * Dn;
  const float* bo = ca_out_b + i * Dn;
  for (int j = t; j < Dn; j += 256) {
    const float* w = wo + (size_t)j * Dn;
    float s0 = 0, s1 = 0, s2 = 0, s3 = 0;
    for (int k = 0; k < Dn; k += 4) {
      s0 += vs[k]*w[k]; s1 += vs[k+1]*w[k+1]; s2 += vs[k+2]*w[k+2]; s3 += vs[k+3]*w[k+3];
    }
    ca_add[((size_t)i * Bn + b) * Dn + j] = s0 + s1 + s2 + s3 + bo[j];
  }
}

// ---------------- embedding: X = tok_emb[ids] + pos_emb ----------------------
__global__ __launch_bounds__(128)
void k_embed(const int* __restrict__ ids, const float* __restrict__ tok,
             const float* __restrict__ pos, float* __restrict__ X,
             u16* __restrict__ Xb) {
  int r = blockIdx.x;
  int l = r & (Ln - 1);
  int id = ids[r];
  int c = threadIdx.x * 4;
  f4 te = *(const f4*)&tok[(size_t)id * Dn + c];
  f4 pe = *(const f4*)&pos[(size_t)l * Dn + c];
  f4 v = te + pe;
  *(f4*)&X[(size_t)r * Dn + c] = v;
  us4 o = { f2bf(v[0]), f2bf(v[1]), f2bf(v[2]), f2bf(v[3]) };
  *(us4*)&Xb[(size_t)r * Dn + c] = o;
}

// ---------------- fused residual add + LayerNorm (bf16 Y) --------------------
__global__ __launch_bounds__(128)
void k_add_ln(float* __restrict__ X, u16* __restrict__ Xb,
              const u16* __restrict__ Y, const float* __restrict__ g,
              const float* __restrict__ be) {
  int r = blockIdx.x, t = threadIdx.x;
  int c = t * 4;
  f4 x = *(const f4*)&X[(size_t)r * Dn + c];
  us4 yb = *(const us4*)&Y[(size_t)r * Dn + c];
  f4 v;
  v[0] = x[0] + bf2f(yb[0]); v[1] = x[1] + bf2f(yb[1]);
  v[2] = x[2] + bf2f(yb[2]); v[3] = x[3] + bf2f(yb[3]);
  float sum = v[0] + v[1] + v[2] + v[3];
  float sq = v[0]*v[0] + v[1]*v[1] + v[2]*v[2] + v[3]*v[3];
  for (int off = 32; off; off >>= 1) {
    sum += __shfl_down(sum, off, 64);
    sq  += __shfl_down(sq,  off, 64);
  }
  __shared__ float red[4];
  int lane = t & 63, w = t >> 6;
  if (!lane) { red[w] = sum; red[2 + w] = sq; }
  __syncthreads();
  sum = red[0] + red[1]; sq = red[2] + red[3];
  float mu = sum * (1.0f / Dn);
  float var = sq * (1.0f / Dn) - mu * mu;
  float rstd = rsqrtf(fmaxf(var, 0.0f) + 1e-5f);
  f4 gg = *(const f4*)&g[c];
  f4 bb = *(const f4*)&be[c];
  f4 o = (v - mu) * rstd * gg + bb;
  *(f4*)&X[(size_t)r * Dn + c] = o;
  us4 ob = { f2bf(o[0]), f2bf(o[1]), f2bf(o[2]), f2bf(o[3]) };
  *(us4*)&Xb[(size_t)r * Dn + c] = ob;
}

// ---------------- fused LN1(X+Y) then LN2(. + CA), bf16 Y --------------------
__global__ __launch_bounds__(128)
void k_add_ln12(float* __restrict__ X, u16* __restrict__ Xb,
                const u16* __restrict__ Y, const float* __restrict__ CA,
                const float* __restrict__ g1, const float* __restrict__ b1,
                const float* __restrict__ g2, const float* __restrict__ b2) {
  int r = blockIdx.x, t = threadIdx.x;
  int c = t * 4;
  __shared__ float red[8];
  int lane = t & 63, w = t >> 6;
  f4 x = *(const f4*)&X[(size_t)r * Dn + c];
  us4 yb = *(const us4*)&Y[(size_t)r * Dn + c];
  f4 v;
  v[0] = x[0] + bf2f(yb[0]); v[1] = x[1] + bf2f(yb[1]);
  v[2] = x[2] + bf2f(yb[2]); v[3] = x[3] + bf2f(yb[3]);
  float sum = v[0] + v[1] + v[2] + v[3];
  float sq = v[0]*v[0] + v[1]*v[1] + v[2]*v[2] + v[3]*v[3];
  for (int off = 32; off; off >>= 1) {
    sum += __shfl_down(sum, off, 64);
    sq  += __shfl_down(sq,  off, 64);
  }
  if (!lane) { red[w] = sum; red[2 + w] = sq; }
  __syncthreads();
  sum = red[0] + red[1]; sq = red[2] + red[3];
  float mu = sum * (1.0f / Dn);
  float var = sq * (1.0f / Dn) - mu * mu;
  float rstd = rsqrtf(fmaxf(var, 0.0f) + 1e-5f);
  f4 g1v = *(const f4*)&g1[c];
  f4 b1v = *(const f4*)&b1[c];
  f4 o1 = (v - mu) * rstd * g1v + b1v;
  f4 ca = *(const f4*)&CA[(size_t)(r >> 7) * Dn + c];
  f4 v2 = o1 + ca;
  float sum2 = v2[0] + v2[1] + v2[2] + v2[3];
  float sq2 = v2[0]*v2[0] + v2[1]*v2[1] + v2[2]*v2[2] + v2[3]*v2[3];
  for (int off = 32; off; off >>= 1) {
    sum2 += __shfl_down(sum2, off, 64);
    sq2  += __shfl_down(sq2,  off, 64);
  }
  if (!lane) { red[4 + w] = sum2; red[6 + w] = sq2; }
  __syncthreads();
  sum2 = red[4] + red[5]; sq2 = red[6] + red[7];
  float mu2 = sum2 * (1.0f / Dn);
  float var2 = sq2 * (1.0f / Dn) - mu2 * mu2;
  float rstd2 = rsqrtf(fmaxf(var2, 0.0f) + 1e-5f);
  f4 g2v = *(const f4*)&g2[c];
  f4 b2v = *(const f4*)&b2[c];
  f4 o2 = (v2 - mu2) * rstd2 * g2v + b2v;
  *(f4*)&X[(size_t)r * Dn + c] = o2;
  us4 ob = { f2bf(o2[0]), f2bf(o2[1]), f2bf(o2[2]), f2bf(o2[3]) };
  *(us4*)&Xb[(size_t)r * Dn + c] = ob;
}

// ---------------- MFMA causal attention (R9/R10 passing kernel, unchanged) ---
__global__ __launch_bounds__(256, 1)
void k_attn_m(const u16* __restrict__ QKV, u16* __restrict__ Ob) {
  constexpr int QS = 0;
  constexpr int KS = 9216;
  constexpr int SFB = 36864;
  constexpr int VTB = 36864 + 66048;
  constexpr int MXB = VTB + 17408;
  constexpr int LXB = MXB + 1024;
  __shared__ __align__(16) char smem[LXB + 1024];
  u16* U = (u16*)smem;
  float* Sf = (float*)(smem + SFB);
  u16* Vt = (u16*)(smem + VTB);
  float* Mx = (float*)(smem + MXB);
  float* Lx = (float*)(smem + LXB);

  int bh = blockIdx.x, b = bh >> 3, h = bh & 7;
  int tid = threadIdx.x, lane = tid & 63, wid = tid >> 6;
  int r = tid & 127, half = tid >> 7;

  {
    const u16* qk = QKV + (size_t)(b * 128 + r) * 1536 + (half ? 512 : 0) + h * 64;
    u16* dst = U + (half ? KS : QS) + r * 72;
    #pragma unroll
    for (int i = 0; i < 64; i += 8)
      *(short8*)(dst + i) = *(const short8*)(qk + i);
    const u16* vsrc = QKV + (size_t)(b * 128 + r) * 1536 + 1024 + h * 64 + half * 32;
    #pragma unroll
    for (int i = 0; i < 32; i += 8) {
      short8 v = *(const short8*)(vsrc + i);
      #pragma unroll
      for (int j = 0; j < 8; j++)
        Vt[(half * 32 + i + j) * 136 + r] = (u16)v[j];
    }
  }
  __syncthreads();

  int qb = wid * 32;
  int fr = lane & 15, qk8 = (lane >> 4) * 8, qrl = (lane >> 4) * 4;
  f32x4 sacc[2][8] = {};
  #pragma unroll
  for (int s = 0; s < 2; s++) {
    short8 av[2], bv[8];
    #pragma unroll
    for (int mi = 0; mi < 2; mi++)
      av[mi] = *(const short8*)(U + QS + (qb + mi * 16 + fr) * 72 + s * 32 + qk8);
    #pragma unroll
    for (int nj = 0; nj < 8; nj++)
      bv[nj] = *(const short8*)(U + KS + (nj * 16 + fr) * 72 + s * 32 + qk8);
    #pragma unroll
    for (int mi = 0; mi < 2; mi++)
      #pragma unroll
      for (int nj = 0; nj < 8; nj++)
        sacc[mi][nj] = __builtin_amdgcn_mfma_f32_16x16x32_bf16(
            av[mi], bv[nj], sacc[mi][nj], 0, 0, 0);
  }
  #pragma unroll
  for (int mi = 0; mi < 2; mi++)
    #pragma unroll
    for (int nj = 0; nj < 8; nj++)
      #pragma unroll
      for (int g = 0; g < 4; g++) {
        int q = qb + mi * 16 + qrl + g;
        int k = nj * 16 + fr;
        Sf[q * 129 + k] = (k <= q) ? sacc[mi][nj][g] * 0.125f : -1e30f;
      }
  __syncthreads();

  int kr = half * 64;
  float m = -1e30f;
  for (int k = 0; k < 64; k++) m = fmaxf(m, Sf[r * 129 + kr + k]);
  Mx[half * 128 + r] = m;
  __syncthreads();
  float mm = fmaxf(Mx[r], Mx[128 + r]);
  float l = 0.0f;
  for (int k = 0; k < 64; k++) {
    float p = __expf(Sf[r * 129 + kr + k] - mm);
    Sf[r * 129 + kr + k] = p;
    l += p;
  }
  Lx[half * 128 + r] = l;
  __syncthreads();
  float linv = 1.0f / (Lx[r] + Lx[128 + r]);
  #pragma unroll
  for (int kc = 0; kc < 8; kc++) {
    short8 pv;
    #pragma unroll
    for (int j = 0; j < 8; j++)
      pv[j] = (short)f2bf(Sf[r * 129 + kr + kc * 8 + j] * linv);
    *(short8*)(U + r * 136 + kr + kc * 8) = pv;
  }
  __syncthreads();

  f32x4 oacc[2][4] = {};
  #pragma unroll
  for (int ks = 0; ks < 4; ks++) {
    short8 av[2], bv[4];
    #pragma unroll
    for (int mi = 0; mi < 2; mi++)
      av[mi] = *(const short8*)(U + (qb + mi * 16 + fr) * 136 + ks * 32 + qk8);
    #pragma unroll
    for (int nj = 0; nj < 4; nj++)
      bv[nj] = *(const short8*)(Vt + (nj * 16 + fr) * 136 + ks * 32 + qk8);
    #pragma unroll
    for (int mi = 0; mi < 2; mi++)
      #pragma unroll
      for (int nj = 0; nj < 4; nj++)
        oacc[mi][nj] = __builtin_amdgcn_mfma_f32_16x16x32_bf16(
            av[mi], bv[nj], oacc[mi][nj], 0, 0, 0);
  }
  #pragma unroll
  for (int mi = 0; mi < 2; mi++)
    #pragma unroll
    for (int nj = 0; nj < 4; nj++)
      #pragma unroll
      for (int g = 0; g < 4; g++) {
        int q = qb + mi * 16 + qrl + g;
        int d = nj * 16 + fr;
        Ob[(size_t)(b * 128 + q) * 512 + h * 64 + d] = f2bf(oacc[mi][nj][g]);
      }
}

// ---------------- layer GEMM (R8-R10 passing kernel, unchanged) --------------
template <int EPI, int BNT>
__global__ __launch_bounds__(256, (BNT == 128 ? 2 : 3))
void k_gemm_bt(const u16* __restrict__ A, const u16* __restrict__ Bw,
               const float* __restrict__ bias, void* __restrict__ Cout,
               int gm, int N, int K, int ldc) {
  constexpr int NREP = BNT / 32;
  constexpr int ASTRIDE = 128 * 64;
  constexpr int BSTRIDE = BNT * 64;
  constexpr int TSTRIDE = BNT + 4;
  constexpr int NLA = 4;
  constexpr int NLB = BNT / 32;
  __shared__ __align__(16) char smem[(ASTRIDE + BSTRIDE) * 4];
  u16* As = (u16*)smem;
  u16* Bs = (u16*)(smem + ASTRIDE * 4);
  float* Ts = (float*)smem;

  int lin = blockIdx.x;
  int bm = lin % gm, bn = lin / gm;
  int tid = threadIdx.x, lane = tid & 63, wid = tid >> 6;
  int wr = wid >> 1, wc = wid & 1;
  int fr = lane & 15, q = lane >> 4;
  f32x4 acc[4][NREP] = {};

  auto stage = [&](int it) {
    int buf = it & 1;
    #pragma unroll
    for (int l = 0; l < NLA; l++) {
      int c = tid + l * 256;
      int row = c >> 3;
      int kcg = (c & 7) ^ (row & 7);
      GLD(A + (size_t)(bm * 128 + row) * K + it * 64 + kcg * 8,
          (char*)(As + buf * ASTRIDE) + c * 16);
    }
    #pragma unroll
    for (int l = 0; l < NLB; l++) {
      int c = tid + l * 256;
      int row = c >> 3;
      int kcg = (c & 7) ^ (row & 7);
      GLD(Bw + (size_t)(bn * BNT + row) * K + it * 64 + kcg * 8,
          (char*)(Bs + buf * BSTRIDE) + c * 16);
    }
  };

  int nt = K >> 6;
  stage(0);
  for (int it = 0; it < nt; ++it) {
    int cur = it & 1;
    if (it + 1 < nt) {
      stage(it + 1);
      if constexpr (BNT == 128) asm volatile("s_waitcnt vmcnt(8)" ::: "memory");
      else                      asm volatile("s_waitcnt vmcnt(6)" ::: "memory");
    } else {
      asm volatile("s_waitcnt vmcnt(0)" ::: "memory");
    }
    __builtin_amdgcn_sched_barrier(0);
    __builtin_amdgcn_s_barrier();
    __builtin_amdgcn_sched_barrier(0);
    short8 av[2][4], bv[2][NREP];
    #pragma unroll
    for (int s = 0; s < 2; s++) {
      #pragma unroll
      for (int mi = 0; mi < 4; mi++) {
        int row = wr * 64 + mi * 16 + fr;
        int phys = (s * 4 + q) ^ (row & 7);
        av[s][mi] = *(const short8*)&As[cur * ASTRIDE + row * 64 + phys * 8];
      }
      #pragma unroll
      for (int nj = 0; nj < NREP; nj++) {
        int row = wc * (BNT / 2) + nj * 16 + fr;
        int phys = (s * 4 + q) ^ (row & 7);
        bv[s][nj] = *(const short8*)&Bs[cur * BSTRIDE + row * 64 + phys * 8];
      }
    }
    #pragma unroll
    for (int s = 0; s < 2; s++)
      #pragma unroll
      for (int mi = 0; mi < 4; mi++)
        #pragma unroll
        for (int nj = 0; nj < NREP; nj++)
          acc[mi][nj] = __builtin_amdgcn_mfma_f32_16x16x32_bf16(
              av[s][mi], bv[s][nj], acc[mi][nj], 0, 0, 0);
    asm volatile("s_waitcnt lgkmcnt(0)" ::: "memory");
    __builtin_amdgcn_sched_barrier(0);
    __builtin_amdgcn_s_barrier();
    __builtin_amdgcn_sched_barrier(0);
  }

  float bb[NREP];
  #pragma unroll
  for (int nj = 0; nj < NREP; nj++) {
    int cg = bn * BNT + wc * (BNT / 2) + nj * 16 + fr;
    bb[nj] = (cg < N) ? bias[cg] : 0.0f;
  }
  int rl0 = (lane >> 4) * 4;
  #pragma unroll
  for (int mi = 0; mi < 4; mi++) {
    #pragma unroll
    for (int nj = 0; nj < NREP; nj++) {
      int colL = wc * (BNT / 2) + nj * 16 + fr;
      #pragma unroll
      for (int r = 0; r < 4; r++)
        Ts[(wr * 16 + rl0 + r) * TSTRIDE + colL] = acc[mi][nj][r] + bb[nj];
    }
    __syncthreads();
    constexpr int ITERS = (32 * BNT) / 256;
    #pragma unroll
    for (int i = 0; i < ITERS; i++) {
      int flat = i * 256 + tid;
      int rowf = flat / BNT, col = flat % BNT;
      float v = Ts[rowf * TSTRIDE + col];
      int row_g = bm * 128 + (rowf >> 4) * 64 + mi * 16 + (rowf & 15);
      int col_g = bn * BNT + col;
      size_t off = (size_t)row_g * ldc + col_g;
      if (EPI == 0) {
        if (col_g < N) ((float*)Cout)[off] = v;
      } else if (EPI == 1) {
        ((u16*)Cout)[off] = f2bf(fmaxf(v, 0.0f));
      } else {
        ((u16*)Cout)[off] = f2bf(v);
      }
    }
    if (mi < 3) __syncthreads();
  }
}

// ---------------- vocab GEMM: 256x192 tile, BK=64, phase-split pipeline ------
// 8 waves (2M x 4N), acc[8][3], av held in registers across phases.
// Buffers: A double (staged 1 K-tile ahead -> never the slot being read),
// B triple (staged 2 ahead, slot j%3). Per iter: 3 phases, each
// {stage || ds_read -> lgkmcnt(0) -> setprio(1) MFMA setprio(0)} -> s_barrier.
// Counted vmcnt gate at phase 0 only: steady vmcnt(5) (=B(kt+1)*3 + A-lo(kt+1)*2
// outstanding; newest-needed A-hi(kt) has 3 phases of latency budget).
// kt=0: vmcnt(2) (prologue B0,B1,A0). last kt: vmcnt(0). LDS 136 KB.
__global__ __launch_bounds__(512, 2)
void k_gemm_v8(const u16* __restrict__ A, const u16* __restrict__ Bw,
               const float* __restrict__ bias, float* __restrict__ Cout,
               int gm, int N, int K, int ldc) {
  constexpr int AST = 256 * 64;                // u16 per A slot (32 KB)
  constexpr int BST = 192 * 64;                // u16 per B slot (24 KB)
  constexpr int TSTRIDE = 192 + 4;
  __shared__ __align__(16) char smem[AST * 2 * 2 + BST * 3 * 2];  // 136 KB
  u16* As = (u16*)smem;                        // [2][AST]
  u16* Bs = (u16*)(smem + AST * 4);            // [3][BST]
  float* Ts = (float*)smem;                    // epilogue alias [32][196]

  int lin = blockIdx.x;
  int bm = lin % gm, bn = lin / gm;            // bm fastest
  int tid = threadIdx.x, lane = tid & 63, wid = tid >> 6;
  int wr = wid >> 2, wc = wid & 3;             // 2M x 4N; wave out 128 x 48
  int fr = lane & 15, q = lane >> 4;
  f32x4 acc[8][3] = {};
  int nt = K >> 6;                             // 8 for K=512

  auto stageAh = [&](int j, int half) {        // one A half-tile: 2 loads/thr
    int sl = j & 1;
    #pragma unroll
    for (int l = 0; l < 2; l++) {
      int c = tid + l * 512;                   // 0..1023
      int row = half * 128 + (c >> 3);
      int kcg = (c & 7) ^ (row & 7);           // inverse-swizzled source chunk
      GLD(A + (size_t)(bm * 256 + row) * K + j * 64 + kcg * 8,
          (char*)(As + sl * AST) + (half * 1024 + c) * 16);
    }
  };
  auto stageB = [&](int j) {                   // full B tile: 3 loads/thr
    int sl = j % 3;
    #pragma unroll
    for (int l = 0; l < 3; l++) {
      int c = tid + l * 512;                   // 0..1535
      int row = c >> 3;                        // 0..191
      int kcg = (c & 7) ^ (row & 7);
      GLD(Bw + (size_t)(bn * 192 + row) * K + j * 64 + kcg * 8,
          (char*)(Bs + sl * BST) + c * 16);
    }
  };

  // prologue: B(0), B(1), A(0)   [issue order matters for vmcnt counts]
  stageB(0);
  if (nt > 1) stageB(1);
  stageAh(0, 0); stageAh(0, 1);

  for (int kt = 0; kt < nt; ++kt) {
    int adb = kt & 1, bsl = kt % 3;
    // ---- phase 0 ----
    if (kt + 1 < nt) stageAh(kt + 1, 0);       // -> A[adb^1][lo], not read now
    if (kt == 0 && nt > 1)      asm volatile("s_waitcnt vmcnt(2)" ::: "memory");
    else if (kt + 1 < nt)       asm volatile("s_waitcnt vmcnt(5)" ::: "memory");
    else                        asm volatile("s_waitcnt vmcnt(0)" ::: "memory");
    __builtin_amdgcn_sched_barrier(0);
    __builtin_amdgcn_s_barrier();              // K-tile kt fully resident
    __builtin_amdgcn_sched_barrier(0);
    short8 av[2][8];
    #pragma unroll
    for (int s = 0; s < 2; s++)
      #pragma unroll
      for (int mi = 0; mi < 8; mi++) {
        int row = wr * 128 + mi * 16 + fr;
        av[s][mi] = *(const short8*)
            &As[adb * AST + row * 64 + ((s * 4 + q) ^ (row & 7)) * 8];
      }
    #pragma unroll
    for (int p = 0; p < 3; p++) {              // phase p computes nj = p
      if (p == 1) { if (kt + 1 < nt) stageAh(kt + 1, 1); }
      if (p == 2) { if (kt + 2 < nt) stageB(kt + 2); }    // -> B[(kt+2)%3]
      #pragma unroll
      for (int s = 0; s < 2; s++) {
        int row = wc * 48 + p * 16 + fr;
        short8 bv = *(const short8*)
            &Bs[bsl * BST + row * 64 + ((s * 4 + q) ^ (row & 7)) * 8];
        asm volatile("s_waitcnt lgkmcnt(0)" ::: "memory");
        __builtin_amdgcn_sched_barrier(0);
        __builtin_amdgcn_s_setprio(1);
        #pragma unroll
        for (int mi = 0; mi < 8; mi++)
          acc[mi][p] = __builtin_amdgcn_mfma_f32_16x16x32_bf16(
              av[s][mi], bv, acc[mi][p], 0, 0, 0);
        __builtin_amdgcn_s_setprio(0);
      }
      __builtin_amdgcn_s_barrier();            // end of phase
      __builtin_amdgcn_sched_barrier(0);
    }
  }

  // ---- epilogue: per mi, 32x192 slab via LDS (aliases A) -> coalesced f32 ---
  float bb[3];
  #pragma unroll
  for (int nj = 0; nj < 3; nj++) {
    int cg = bn * 192 + wc * 48 + nj * 16 + fr;
    bb[nj] = (cg < N) ? bias[cg] : 0.0f;
  }
  int rl0 = (lane >> 4) * 4;
  #pragma unroll
  for (int mi = 0; mi < 8; mi++) {
    #pragma unroll
    for (int nj = 0; nj < 3; nj++) {
      int colL = wc * 48 + nj * 16 + fr;
      #pragma unroll
      for (int r = 0; r < 4; r++)
        Ts[(wr * 16 + rl0 + r) * TSTRIDE + colL] = acc[mi][nj][r] + bb[nj];
    }
    __syncthreads();
    #pragma unroll
    for (int i = 0; i < 12; i++) {             // 32*192 f32 / 512 thr
      int flat = i * 512 + tid;
      int rowf = flat / 192, col = flat % 192;
      float v = Ts[rowf * TSTRIDE + col];
      int row_g = bm * 256 + (rowf >> 4) * 128 + mi * 16 + (rowf & 15);
      int col_g = bn * 192 + col;
      if (col_g < N)
        Cout[(size_t)row_g * ldc + col_g] = v;
    }
    if (mi < 7) __syncthreads();
  }
}

// =============================================================================
extern "C" void kernel_launch(void* const* d_in, const int* in_sizes, int n_in,
                              void* d_out, int out_size, void* d_ws, size_t ws_size,
                              hipStream_t stream) {
  const float* z        = (const float*)d_in[0];
  const int*   ids      = (const int*)d_in[1];
  const float* tok      = (const float*)d_in[2];
  const float* pos      = (const float*)d_in[3];
  const float* lp_w     = (const float*)d_in[4];
  const float* lp_b     = (const float*)d_in[5];
  const float* lp_g     = (const float*)d_in[6];
  const float* lp_be    = (const float*)d_in[7];
  const float* sa_qkv_w = (const float*)d_in[8];
  const float* sa_qkv_b = (const float*)d_in[9];
  const float* sa_out_w = (const float*)d_in[10];
  const float* sa_out_b = (const float*)d_in[11];
  const float* ca_qkv_w = (const float*)d_in[12];
  const float* ca_qkv_b = (const float*)d_in[13];
  const float* ca_out_w = (const float*)d_in[14];
  const float* ca_out_b = (const float*)d_in[15];
  const float* ln1_g    = (const float*)d_in[16];
  const float* ln1_b    = (const float*)d_in[17];
  const float* ln2_g    = (const float*)d_in[18];
  const float* ln2_b    = (const float*)d_in[19];
  const float* ln3_g    = (const float*)d_in[20];
  const float* ln3_b    = (const float*)d_in[21];
  const float* ff1_w    = (const float*)d_in[22];
  const float* ff1_b    = (const float*)d_in[23];
  const float* ff2_w    = (const float*)d_in[24];
  const float* ff2_b    = (const float*)d_in[25];
  const float* op_w     = (const float*)d_in[26];
  const float* op_b     = (const float*)d_in[27];

  char* ws = (char*)d_ws;
  float* X      = (float*)(ws + 0);           // 4096x512 f32
  u16*   Yb     = (u16*)(ws + 8388608);       // 4096x512 bf16
  u16*   QKVb   = (u16*)(ws + 16777216);      // 4096x1536 bf16
  u16*   Xb     = (u16*)(ws + 29360128);      // 4096x512 bf16
  u16*   Ob     = (u16*)(ws + 33554432);      // 4096x512 bf16
  u16*   H1b    = (u16*)(ws + 37748736);      // 4096x2048 bf16
  float* mem    = (float*)(ws + 54525952);    // 32x512 f32
  float* ca_add = (float*)(ws + 54657024);    // 4x32x512 f32
  u16*   Wa     = (u16*)(ws + 55050240);      // weight arena bf16 (contiguous)

  u16* Wqkv = Wa;                              // 4 x 1536x512
  u16* Wout = Wa + 3145728;                    // 4 x 512x512
  u16* Wff1 = Wa + 4194304;                    // 4 x 2048x512
  u16* Wff2 = Wa + 8388608;                    // 4 x 512x2048
  u16* Wop  = Wa + 12582912;                   // 50304x512 (zero-padded tail)

  k_latent_mem<<<Bn, 256, 0, stream>>>(z, lp_w, lp_b, lp_g, lp_be, mem);
  k_ca<<<4 * Bn, 256, 0, stream>>>(mem, ca_qkv_w, ca_qkv_b, ca_out_w, ca_out_b, ca_add);
  k_embed<<<Bn * Ln, 128, 0, stream>>>(ids, tok, pos, X, Xb);
  k_cvt_all<<<2048, 256, 0, stream>>>(sa_qkv_w, sa_out_w, ff1_w, ff2_w, op_w,
                                      (us4*)Wa);

  const int M = Bn * Ln;  // 4096
  for (int i = 0; i < 4; i++) {
    k_gemm_bt<2, 128><<<32 * 12, 256, 0, stream>>>(
        Xb, Wqkv + (size_t)i * 1536 * Dn, sa_qkv_b + i * 1536, QKVb, 32, 1536, Dn, 1536);
    k_attn_m<<<Bn * Hn, 256, 0, stream>>>(QKVb, Ob);
    k_gemm_bt<2, 64><<<32 * 8, 256, 0, stream>>>(
        Ob, Wout + (size_t)i * Dn * Dn, sa_out_b + i * Dn, Yb, 32, Dn, Dn, Dn);
    k_add_ln12<<<M, 128, 0, stream>>>(X, Xb, Yb, ca_add + (size_t)i * Bn * Dn,
                                      ln1_g + i * Dn, ln1_b + i * Dn,
                                      ln2_g + i * Dn, ln2_b + i * Dn);
    k_gemm_bt<1, 128><<<32 * 16, 256, 0, stream>>>(
        Xb, Wff1 + (size_t)i * DFn * Dn, ff1_b + i * DFn, H1b, 32, DFn, Dn, DFn);
    k_gemm_bt<2, 64><<<32 * 8, 256, 0, stream>>>(
        H1b, Wff2 + (size_t)i * Dn * DFn, ff2_b + i * Dn, Yb, 32, Dn, DFn, Dn);
    k_add_ln<<<M, 128, 0, stream>>>(X, Xb, Yb, ln3_g + i * Dn, ln3_b + i * Dn);
  }

  // final vocab projection -> d_out (f32): 256x192 tiles, 16 x 262 grid
  k_gemm_v8<<<16 * 262, 512, 0, stream>>>(
      Xb, Wop, op_b, (float*)d_out, 16, Vn, Dn, Vn);
}

// Round 12
// 828.114 us; speedup vs baseline: 1.0418x; 1.0418x over previous
//
#include <hip/hip_runtime.h>
#include <math.h>

typedef __attribute__((ext_vector_type(8))) short short8;
typedef __attribute__((ext_vector_type(4))) float f32x4;
typedef __attribute__((ext_vector_type(4))) float f4;
typedef __attribute__((ext_vector_type(4))) unsigned short us4;
typedef unsigned short u16;

#define Bn 32
#define Ln 128
#define Dn 512
#define LATn 256
#define Vn 50257
#define VPAD 50304
#define DFn 2048
#define Hn 8
#define HDn 64

#define GLD(src, dst) __builtin_amdgcn_global_load_lds( \
    (const __attribute__((address_space(1))) unsigned int*)(src), \
    (__attribute__((address_space(3))) unsigned int*)(dst), 16, 0, 0)

__device__ __forceinline__ u16 f2bf(float f) {
  union { float f; unsigned u; } v; v.f = f;
  unsigned r = 0x7FFFu + ((v.u >> 16) & 1u);
  return (u16)((v.u + r) >> 16);
}
__device__ __forceinline__ float bf2f(u16 u) {
  union { unsigned u; float f; } v; v.u = ((unsigned)u) << 16;
  return v.f;
}

// ---------------- all weights f32 -> bf16, one kernel (contiguous dst arena) -
__global__ __launch_bounds__(256)
void k_cvt_all(const float* __restrict__ s0, const float* __restrict__ s1,
               const float* __restrict__ s2, const float* __restrict__ s3,
               const float* __restrict__ s4, us4* __restrict__ dst) {
  const int C0 = 786432;    // qkv  4*1536*512/4
  const int C1 = 1048576;   // +out 4*512*512/4
  const int C2 = 2097152;   // +ff1 4*2048*512/4
  const int C3 = 3145728;   // +ff2
  const int C4 = 9584640;   // +op (VPAD*512/4)
  const int OPN4 = 6432896; // op real Vn*512/4
  int i = blockIdx.x * blockDim.x + threadIdx.x;
  int stride = gridDim.x * blockDim.x;
  for (; i < C4; i += stride) {
    const f4* src; int off; bool valid = true;
    if (i < C0)      { src = (const f4*)s0; off = i; }
    else if (i < C1) { src = (const f4*)s1; off = i - C0; }
    else if (i < C2) { src = (const f4*)s2; off = i - C1; }
    else if (i < C3) { src = (const f4*)s3; off = i - C2; }
    else             { src = (const f4*)s4; off = i - C3; valid = off < OPN4; }
    us4 o;
    if (valid) {
      f4 v = src[off];
      o[0] = f2bf(v[0]); o[1] = f2bf(v[1]); o[2] = f2bf(v[2]); o[3] = f2bf(v[3]);
    } else { o[0] = 0; o[1] = 0; o[2] = 0; o[3] = 0; }
    dst[i] = o;
  }
}

// ---------------- latent_proj: mem = LN(GELU(z @ lp_w.T + lp_b)) -------------
__global__ __launch_bounds__(256)
void k_latent_mem(const float* __restrict__ z, const float* __restrict__ lp_w,
                  const float* __restrict__ lp_b, const float* __restrict__ g,
                  const float* __restrict__ be, float* __restrict__ mem) {
  __shared__ float zs[LATn];
  __shared__ float red[16];
  int b = blockIdx.x, t = threadIdx.x;
  zs[t] = z[b * LATn + t];
  __syncthreads();
  float h[2];
  #pragma unroll
  for (int j = 0; j < 2; j++) {
    int oj = t + j * 256;
    const float* w = lp_w + (size_t)oj * LATn;
    float s0 = 0, s1 = 0, s2 = 0, s3 = 0;
    for (int k = 0; k < LATn; k += 4) {
      s0 += zs[k] * w[k]; s1 += zs[k+1] * w[k+1];
      s2 += zs[k+2] * w[k+2]; s3 += zs[k+3] * w[k+3];
    }
    float x = s0 + s1 + s2 + s3 + lp_b[oj];
    h[j] = 0.5f * x * (1.0f + erff(x * 0.70710678118654752f));
  }
  float sum = h[0] + h[1], sq = h[0]*h[0] + h[1]*h[1];
  for (int off = 32; off; off >>= 1) {
    sum += __shfl_down(sum, off, 64);
    sq  += __shfl_down(sq,  off, 64);
  }
  int lane = t & 63, wid = t >> 6;
  if (!lane) { red[wid] = sum; red[8 + wid] = sq; }
  __syncthreads();
  float ts = red[0] + red[1] + red[2] + red[3];
  float tq = red[8] + red[9] + red[10] + red[11];
  float mu = ts * (1.0f / Dn);
  float var = tq * (1.0f / Dn) - mu * mu;
  float rstd = rsqrtf(fmaxf(var, 0.0f) + 1e-5f);
  #pragma unroll
  for (int j = 0; j < 2; j++) {
    int oj = t + j * 256;
    mem[b * Dn + oj] = (h[j] - mu) * rstd * g[oj] + be[oj];
  }
}

// ------------- cross-attention precompute (Lk=1 => softmax==1 => o = v) ------
__global__ __launch_bounds__(256)
void k_ca(const float* __restrict__ mem, const float* __restrict__ ca_qkv_w,
          const float* __restrict__ ca_qkv_b, const float* __restrict__ ca_out_w,
          const float* __restrict__ ca_out_b, float* __restrict__ ca_add) {
  int blk = blockIdx.x;
  int i = blk >> 5, b = blk & 31, t = threadIdx.x;
  __shared__ float ms[Dn];
  __shared__ float vs[Dn];
  ms[t] = mem[b * Dn + t];
  ms[t + 256] = mem[b * Dn + t + 256];
  __syncthreads();
  const float* wv = ca_qkv_w + ((size_t)i * 1536 + 1024) * Dn;
  const float* bv = ca_qkv_b + i * 1536 + 1024;
  for (int j = t; j < Dn; j += 256) {
    const float* w = wv + (size_t)j * Dn;
    float s0 = 0, s1 = 0, s2 = 0, s3 = 0;
    for (int k = 0; k < Dn; k += 4) {
      s0 += ms[k]*w[k]; s1 += ms[k+1]*w[k+1]; s2 += ms[k+2]*w[k+2]; s3 += ms[k+3]*w[k+3];
    }
    vs[j] = s0 + s1 + s2 + s3 + bv[j];
  }
  __syncthreads();
  const float* wo = ca_out_w + (size_t)i * Dn * Dn;
  const float* bo = ca_out_b + i * Dn;
  for (int j = t; j < Dn; j += 256) {
    const float* w = wo + (size_t)j * Dn;
    float s0 = 0, s1 = 0, s2 = 0, s3 = 0;
    for (int k = 0; k < Dn; k += 4) {
      s0 += vs[k]*w[k]; s1 += vs[k+1]*w[k+1]; s2 += vs[k+2]*w[k+2]; s3 += vs[k+3]*w[k+3];
    }
    ca_add[((size_t)i * Bn + b) * Dn + j] = s0 + s1 + s2 + s3 + bo[j];
  }
}

// ---------------- embedding: X = tok_emb[ids] + pos_emb ----------------------
__global__ __launch_bounds__(128)
void k_embed(const int* __restrict__ ids, const float* __restrict__ tok,
             const float* __restrict__ pos, float* __restrict__ X,
             u16* __restrict__ Xb) {
  int r = blockIdx.x;
  int l = r & (Ln - 1);
  int id = ids[r];
  int c = threadIdx.x * 4;
  f4 te = *(const f4*)&tok[(size_t)id * Dn + c];
  f4 pe = *(const f4*)&pos[(size_t)l * Dn + c];
  f4 v = te + pe;
  *(f4*)&X[(size_t)r * Dn + c] = v;
  us4 o = { f2bf(v[0]), f2bf(v[1]), f2bf(v[2]), f2bf(v[3]) };
  *(us4*)&Xb[(size_t)r * Dn + c] = o;
}

// ---------------- fused residual add + LayerNorm (bf16 Y) --------------------
__global__ __launch_bounds__(128)
void k_add_ln(float* __restrict__ X, u16* __restrict__ Xb,
              const u16* __restrict__ Y, const float* __restrict__ g,
              const float* __restrict__ be) {
  int r = blockIdx.x, t = threadIdx.x;
  int c = t * 4;
  f4 x = *(const f4*)&X[(size_t)r * Dn + c];
  us4 yb = *(const us4*)&Y[(size_t)r * Dn + c];
  f4 v;
  v[0] = x[0] + bf2f(yb[0]); v[1] = x[1] + bf2f(yb[1]);
  v[2] = x[2] + bf2f(yb[2]); v[3] = x[3] + bf2f(yb[3]);
  float sum = v[0] + v[1] + v[2] + v[3];
  float sq = v[0]*v[0] + v[1]*v[1] + v[2]*v[2] + v[3]*v[3];
  for (int off = 32; off; off >>= 1) {
    sum += __shfl_down(sum, off, 64);
    sq  += __shfl_down(sq,  off, 64);
  }
  __shared__ float red[4];
  int lane = t & 63, w = t >> 6;
  if (!lane) { red[w] = sum; red[2 + w] = sq; }
  __syncthreads();
  sum = red[0] + red[1]; sq = red[2] + red[3];
  float mu = sum * (1.0f / Dn);
  float var = sq * (1.0f / Dn) - mu * mu;
  float rstd = rsqrtf(fmaxf(var, 0.0f) + 1e-5f);
  f4 gg = *(const f4*)&g[c];
  f4 bb = *(const f4*)&be[c];
  f4 o = (v - mu) * rstd * gg + bb;
  *(f4*)&X[(size_t)r * Dn + c] = o;
  us4 ob = { f2bf(o[0]), f2bf(o[1]), f2bf(o[2]), f2bf(o[3]) };
  *(us4*)&Xb[(size_t)r * Dn + c] = ob;
}

// ---------------- fused LN1(X+Y) then LN2(. + CA), bf16 Y --------------------
__global__ __launch_bounds__(128)
void k_add_ln12(float* __restrict__ X, u16* __restrict__ Xb,
                const u16* __restrict__ Y, const float* __restrict__ CA,
                const float* __restrict__ g1, const float* __restrict__ b1,
                const float* __restrict__ g2, const float* __restrict__ b2) {
  int r = blockIdx.x, t = threadIdx.x;
  int c = t * 4;
  __shared__ float red[8];
  int lane = t & 63, w = t >> 6;
  f4 x = *(const f4*)&X[(size_t)r * Dn + c];
  us4 yb = *(const us4*)&Y[(size_t)r * Dn + c];
  f4 v;
  v[0] = x[0] + bf2f(yb[0]); v[1] = x[1] + bf2f(yb[1]);
  v[2] = x[2] + bf2f(yb[2]); v[3] = x[3] + bf2f(yb[3]);
  float sum = v[0] + v[1] + v[2] + v[3];
  float sq = v[0]*v[0] + v[1]*v[1] + v[2]*v[2] + v[3]*v[3];
  for (int off = 32; off; off >>= 1) {
    sum += __shfl_down(sum, off, 64);
    sq  += __shfl_down(sq,  off, 64);
  }
  if (!lane) { red[w] = sum; red[2 + w] = sq; }
  __syncthreads();
  sum = red[0] + red[1]; sq = red[2] + red[3];
  float mu = sum * (1.0f / Dn);
  float var = sq * (1.0f / Dn) - mu * mu;
  float rstd = rsqrtf(fmaxf(var, 0.0f) + 1e-5f);
  f4 g1v = *(const f4*)&g1[c];
  f4 b1v = *(const f4*)&b1[c];
  f4 o1 = (v - mu) * rstd * g1v + b1v;
  f4 ca = *(const f4*)&CA[(size_t)(r >> 7) * Dn + c];
  f4 v2 = o1 + ca;
  float sum2 = v2[0] + v2[1] + v2[2] + v2[3];
  float sq2 = v2[0]*v2[0] + v2[1]*v2[1] + v2[2]*v2[2] + v2[3]*v2[3];
  for (int off = 32; off; off >>= 1) {
    sum2 += __shfl_down(sum2, off, 64);
    sq2  += __shfl_down(sq2,  off, 64);
  }
  if (!lane) { red[4 + w] = sum2; red[6 + w] = sq2; }
  __syncthreads();
  sum2 = red[4] + red[5]; sq2 = red[6] + red[7];
  float mu2 = sum2 * (1.0f / Dn);
  float var2 = sq2 * (1.0f / Dn) - mu2 * mu2;
  float rstd2 = rsqrtf(fmaxf(var2, 0.0f) + 1e-5f);
  f4 g2v = *(const f4*)&g2[c];
  f4 b2v = *(const f4*)&b2[c];
  f4 o2 = (v2 - mu2) * rstd2 * g2v + b2v;
  *(f4*)&X[(size_t)r * Dn + c] = o2;
  us4 ob = { f2bf(o2[0]), f2bf(o2[1]), f2bf(o2[2]), f2bf(o2[3]) };
  *(us4*)&Xb[(size_t)r * Dn + c] = ob;
}

// ---------------- MFMA causal attention (R9/R10 passing kernel, unchanged) ---
__global__ __launch_bounds__(256, 1)
void k_attn_m(const u16* __restrict__ QKV, u16* __restrict__ Ob) {
  constexpr int QS = 0;
  constexpr int KS = 9216;
  constexpr int SFB = 36864;
  constexpr int VTB = 36864 + 66048;
  constexpr int MXB = VTB + 17408;
  constexpr int LXB = MXB + 1024;
  __shared__ __align__(16) char smem[LXB + 1024];
  u16* U = (u16*)smem;
  float* Sf = (float*)(smem + SFB);
  u16* Vt = (u16*)(smem + VTB);
  float* Mx = (float*)(smem + MXB);
  float* Lx = (float*)(smem + LXB);

  int bh = blockIdx.x, b = bh >> 3, h = bh & 7;
  int tid = threadIdx.x, lane = tid & 63, wid = tid >> 6;
  int r = tid & 127, half = tid >> 7;

  {
    const u16* qk = QKV + (size_t)(b * 128 + r) * 1536 + (half ? 512 : 0) + h * 64;
    u16* dst = U + (half ? KS : QS) + r * 72;
    #pragma unroll
    for (int i = 0; i < 64; i += 8)
      *(short8*)(dst + i) = *(const short8*)(qk + i);
    const u16* vsrc = QKV + (size_t)(b * 128 + r) * 1536 + 1024 + h * 64 + half * 32;
    #pragma unroll
    for (int i = 0; i < 32; i += 8) {
      short8 v = *(const short8*)(vsrc + i);
      #pragma unroll
      for (int j = 0; j < 8; j++)
        Vt[(half * 32 + i + j) * 136 + r] = (u16)v[j];
    }
  }
  __syncthreads();

  int qb = wid * 32;
  int fr = lane & 15, qk8 = (lane >> 4) * 8, qrl = (lane >> 4) * 4;
  f32x4 sacc[2][8] = {};
  #pragma unroll
  for (int s = 0; s < 2; s++) {
    short8 av[2], bv[8];
    #pragma unroll
    for (int mi = 0; mi < 2; mi++)
      av[mi] = *(const short8*)(U + QS + (qb + mi * 16 + fr) * 72 + s * 32 + qk8);
    #pragma unroll
    for (int nj = 0; nj < 8; nj++)
      bv[nj] = *(const short8*)(U + KS + (nj * 16 + fr) * 72 + s * 32 + qk8);
    #pragma unroll
    for (int mi = 0; mi < 2; mi++)
      #pragma unroll
      for (int nj = 0; nj < 8; nj++)
        sacc[mi][nj] = __builtin_amdgcn_mfma_f32_16x16x32_bf16(
            av[mi], bv[nj], sacc[mi][nj], 0, 0, 0);
  }
  #pragma unroll
  for (int mi = 0; mi < 2; mi++)
    #pragma unroll
    for (int nj = 0; nj < 8; nj++)
      #pragma unroll
      for (int g = 0; g < 4; g++) {
        int q = qb + mi * 16 + qrl + g;
        int k = nj * 16 + fr;
        Sf[q * 129 + k] = (k <= q) ? sacc[mi][nj][g] * 0.125f : -1e30f;
      }
  __syncthreads();

  int kr = half * 64;
  float m = -1e30f;
  for (int k = 0; k < 64; k++) m = fmaxf(m, Sf[r * 129 + kr + k]);
  Mx[half * 128 + r] = m;
  __syncthreads();
  float mm = fmaxf(Mx[r], Mx[128 + r]);
  float l = 0.0f;
  for (int k = 0; k < 64; k++) {
    float p = __expf(Sf[r * 129 + kr + k] - mm);
    Sf[r * 129 + kr + k] = p;
    l += p;
  }
  Lx[half * 128 + r] = l;
  __syncthreads();
  float linv = 1.0f / (Lx[r] + Lx[128 + r]);
  #pragma unroll
  for (int kc = 0; kc < 8; kc++) {
    short8 pv;
    #pragma unroll
    for (int j = 0; j < 8; j++)
      pv[j] = (short)f2bf(Sf[r * 129 + kr + kc * 8 + j] * linv);
    *(short8*)(U + r * 136 + kr + kc * 8) = pv;
  }
  __syncthreads();

  f32x4 oacc[2][4] = {};
  #pragma unroll
  for (int ks = 0; ks < 4; ks++) {
    short8 av[2], bv[4];
    #pragma unroll
    for (int mi = 0; mi < 2; mi++)
      av[mi] = *(const short8*)(U + (qb + mi * 16 + fr) * 136 + ks * 32 + qk8);
    #pragma unroll
    for (int nj = 0; nj < 4; nj++)
      bv[nj] = *(const short8*)(Vt + (nj * 16 + fr) * 136 + ks * 32 + qk8);
    #pragma unroll
    for (int mi = 0; mi < 2; mi++)
      #pragma unroll
      for (int nj = 0; nj < 4; nj++)
        oacc[mi][nj] = __builtin_amdgcn_mfma_f32_16x16x32_bf16(
            av[mi], bv[nj], oacc[mi][nj], 0, 0, 0);
  }
  #pragma unroll
  for (int mi = 0; mi < 2; mi++)
    #pragma unroll
    for (int nj = 0; nj < 4; nj++)
      #pragma unroll
      for (int g = 0; g < 4; g++) {
        int q = qb + mi * 16 + qrl + g;
        int d = nj * 16 + fr;
        Ob[(size_t)(b * 128 + q) * 512 + h * 64 + d] = f2bf(oacc[mi][nj][g]);
      }
}

// ---------------- layer GEMM (R8-R10 passing kernel, unchanged) --------------
template <int EPI, int BNT>
__global__ __launch_bounds__(256, (BNT == 128 ? 2 : 3))
void k_gemm_bt(const u16* __restrict__ A, const u16* __restrict__ Bw,
               const float* __restrict__ bias, void* __restrict__ Cout,
               int gm, int N, int K, int ldc) {
  constexpr int NREP = BNT / 32;
  constexpr int ASTRIDE = 128 * 64;
  constexpr int BSTRIDE = BNT * 64;
  constexpr int TSTRIDE = BNT + 4;
  constexpr int NLA = 4;
  constexpr int NLB = BNT / 32;
  __shared__ __align__(16) char smem[(ASTRIDE + BSTRIDE) * 4];
  u16* As = (u16*)smem;
  u16* Bs = (u16*)(smem + ASTRIDE * 4);
  float* Ts = (float*)smem;

  int lin = blockIdx.x;
  int bm = lin % gm, bn = lin / gm;
  int tid = threadIdx.x, lane = tid & 63, wid = tid >> 6;
  int wr = wid >> 1, wc = wid & 1;
  int fr = lane & 15, q = lane >> 4;
  f32x4 acc[4][NREP] = {};

  auto stage = [&](int it) {
    int buf = it & 1;
    #pragma unroll
    for (int l = 0; l < NLA; l++) {
      int c = tid + l * 256;
      int row = c >> 3;
      int kcg = (c & 7) ^ (row & 7);
      GLD(A + (size_t)(bm * 128 + row) * K + it * 64 + kcg * 8,
          (char*)(As + buf * ASTRIDE) + c * 16);
    }
    #pragma unroll
    for (int l = 0; l < NLB; l++) {
      int c = tid + l * 256;
      int row = c >> 3;
      int kcg = (c & 7) ^ (row & 7);
      GLD(Bw + (size_t)(bn * BNT + row) * K + it * 64 + kcg * 8,
          (char*)(Bs + buf * BSTRIDE) + c * 16);
    }
  };

  int nt = K >> 6;
  stage(0);
  for (int it = 0; it < nt; ++it) {
    int cur = it & 1;
    if (it + 1 < nt) {
      stage(it + 1);
      if constexpr (BNT == 128) asm volatile("s_waitcnt vmcnt(8)" ::: "memory");
      else                      asm volatile("s_waitcnt vmcnt(6)" ::: "memory");
    } else {
      asm volatile("s_waitcnt vmcnt(0)" ::: "memory");
    }
    __builtin_amdgcn_sched_barrier(0);
    __builtin_amdgcn_s_barrier();
    __builtin_amdgcn_sched_barrier(0);
    short8 av[2][4], bv[2][NREP];
    #pragma unroll
    for (int s = 0; s < 2; s++) {
      #pragma unroll
      for (int mi = 0; mi < 4; mi++) {
        int row = wr * 64 + mi * 16 + fr;
        int phys = (s * 4 + q) ^ (row & 7);
        av[s][mi] = *(const short8*)&As[cur * ASTRIDE + row * 64 + phys * 8];
      }
      #pragma unroll
      for (int nj = 0; nj < NREP; nj++) {
        int row = wc * (BNT / 2) + nj * 16 + fr;
        int phys = (s * 4 + q) ^ (row & 7);
        bv[s][nj] = *(const short8*)&Bs[cur * BSTRIDE + row * 64 + phys * 8];
      }
    }
    #pragma unroll
    for (int s = 0; s < 2; s++)
      #pragma unroll
      for (int mi = 0; mi < 4; mi++)
        #pragma unroll
        for (int nj = 0; nj < NREP; nj++)
          acc[mi][nj] = __builtin_amdgcn_mfma_f32_16x16x32_bf16(
              av[s][mi], bv[s][nj], acc[mi][nj], 0, 0, 0);
    asm volatile("s_waitcnt lgkmcnt(0)" ::: "memory");
    __builtin_amdgcn_sched_barrier(0);
    __builtin_amdgcn_s_barrier();
    __builtin_amdgcn_sched_barrier(0);
  }

  float bb[NREP];
  #pragma unroll
  for (int nj = 0; nj < NREP; nj++) {
    int cg = bn * BNT + wc * (BNT / 2) + nj * 16 + fr;
    bb[nj] = (cg < N) ? bias[cg] : 0.0f;
  }
  int rl0 = (lane >> 4) * 4;
  #pragma unroll
  for (int mi = 0; mi < 4; mi++) {
    #pragma unroll
    for (int nj = 0; nj < NREP; nj++) {
      int colL = wc * (BNT / 2) + nj * 16 + fr;
      #pragma unroll
      for (int r = 0; r < 4; r++)
        Ts[(wr * 16 + rl0 + r) * TSTRIDE + colL] = acc[mi][nj][r] + bb[nj];
    }
    __syncthreads();
    constexpr int ITERS = (32 * BNT) / 256;
    #pragma unroll
    for (int i = 0; i < ITERS; i++) {
      int flat = i * 256 + tid;
      int rowf = flat / BNT, col = flat % BNT;
      float v = Ts[rowf * TSTRIDE + col];
      int row_g = bm * 128 + (rowf >> 4) * 64 + mi * 16 + (rowf & 15);
      int col_g = bn * BNT + col;
      size_t off = (size_t)row_g * ldc + col_g;
      if (EPI == 0) {
        if (col_g < N) ((float*)Cout)[off] = v;
      } else if (EPI == 1) {
        ((u16*)Cout)[off] = f2bf(fmaxf(v, 0.0f));
      } else {
        ((u16*)Cout)[off] = f2bf(v);
      }
    }
    if (mi < 3) __syncthreads();
  }
}

// ---------------- vocab GEMM: 256x256 tile, BK=64, 8 waves (R10 proven) ------
// ONLY change vs R10: 2D XCD-chunked block mapping. Grid 3200 = 8 chunks x
// (8 bm x 50 bn). chunk = lin&7 (round-robin -> one XCD per chunk):
// bm-half = chunk&1 (A working set 2 MB, resident in 4 MB L2), bn-quarter =
// chunk>>1 (B panels stream, 8 same-panel readers temporally adjacent).
// bn >= 197 blocks exit before any barrier. Protocol byte-identical to R10.
__global__ __launch_bounds__(512, 2)
void k_gemm_v256(const u16* __restrict__ A, const u16* __restrict__ Bw,
                 const float* __restrict__ bias, float* __restrict__ Cout,
                 int gm, int N, int K, int ldc) {
  constexpr int ASTRIDE = 256 * 64;            // u16 per A buffer (32 KB)
  constexpr int BSTRIDE = 256 * 64;            // u16 per B buffer (32 KB)
  constexpr int TSTRIDE = 256 + 4;
  __shared__ __align__(16) char smem[(ASTRIDE + BSTRIDE) * 4];   // 128 KB
  u16* As = (u16*)smem;
  u16* Bs = (u16*)(smem + ASTRIDE * 4);
  float* Ts = (float*)smem;                    // epilogue alias [32][260]

  int lin = blockIdx.x;
  int xcd = lin & 7, pos = lin >> 3;           // chunk, 400 positions/chunk
  int bm = ((xcd & 1) << 3) + (pos & 7);       // 0..15 (bm-half per chunk)
  int bn = (xcd >> 1) * 50 + (pos >> 3);       // 0..199 (bn-quarter per chunk)
  if (bn >= 197) return;                       // before any barrier

  int tid = threadIdx.x, lane = tid & 63, wid = tid >> 6;  // 8 waves
  int wr = wid >> 2, wc = wid & 3;             // 2 x 4 wave grid (128x64 each)
  int fr = lane & 15, q = lane >> 4;
  f32x4 acc[8][4] = {};

  auto stage = [&](int it) {
    int buf = it & 1;
    #pragma unroll
    for (int l = 0; l < 4; l++) {              // A: 256 rows x 8 chunks / 512
      int c = tid + l * 512;
      int row = c >> 3;
      int kcg = (c & 7) ^ (row & 7);
      GLD(A + (size_t)(bm * 256 + row) * K + it * 64 + kcg * 8,
          (char*)(As + buf * ASTRIDE) + c * 16);
    }
    #pragma unroll
    for (int l = 0; l < 4; l++) {              // B: 256 rows x 8 chunks / 512
      int c = tid + l * 512;
      int row = c >> 3;
      int rowg = bn * 256 + row;
      if (rowg > VPAD - 1) rowg = VPAD - 1;    // clamp to zeroed pad row
      int kcg = (c & 7) ^ (row & 7);
      GLD(Bw + (size_t)rowg * K + it * 64 + kcg * 8,
          (char*)(Bs + buf * BSTRIDE) + c * 16);
    }
  };

  int nt = K >> 6;
  stage(0);
  for (int it = 0; it < nt; ++it) {
    int cur = it & 1;
    if (it + 1 < nt) {
      stage(it + 1);                            // writes buf cur^1 (released)
      asm volatile("s_waitcnt vmcnt(8)" ::: "memory");  // stage(it) landed
    } else {
      asm volatile("s_waitcnt vmcnt(0)" ::: "memory");
    }
    __builtin_amdgcn_sched_barrier(0);
    __builtin_amdgcn_s_barrier();               // buf cur ready for all waves
    __builtin_amdgcn_sched_barrier(0);
    #pragma unroll
    for (int s = 0; s < 2; s++) {
      short8 av[8], bv[4];
      #pragma unroll
      for (int mi = 0; mi < 8; mi++) {
        int row = wr * 128 + mi * 16 + fr;
        int phys = (s * 4 + q) ^ (row & 7);
        av[mi] = *(const short8*)&As[cur * ASTRIDE + row * 64 + phys * 8];
      }
      #pragma unroll
      for (int nj = 0; nj < 4; nj++) {
        int row = wc * 64 + nj * 16 + fr;
        int phys = (s * 4 + q) ^ (row & 7);
        bv[nj] = *(const short8*)&Bs[cur * BSTRIDE + row * 64 + phys * 8];
      }
      #pragma unroll
      for (int mi = 0; mi < 8; mi++)
        #pragma unroll
        for (int nj = 0; nj < 4; nj++)
          acc[mi][nj] = __builtin_amdgcn_mfma_f32_16x16x32_bf16(
              av[mi], bv[nj], acc[mi][nj], 0, 0, 0);
    }
    asm volatile("s_waitcnt lgkmcnt(0)" ::: "memory");  // my reads done
    __builtin_amdgcn_sched_barrier(0);
    __builtin_amdgcn_s_barrier();               // buf cur released for restage
    __builtin_amdgcn_sched_barrier(0);
  }

  // epilogue: per mi, 32 rows x 256 cols slab via LDS -> coalesced f32 stores
  float bb[4];
  #pragma unroll
  for (int nj = 0; nj < 4; nj++) {
    int cg = bn * 256 + wc * 64 + nj * 16 + fr;
    bb[nj] = (cg < N) ? bias[cg] : 0.0f;
  }
  int rl0 = (lane >> 4) * 4;
  #pragma unroll
  for (int mi = 0; mi < 8; mi++) {
    #pragma unroll
    for (int nj = 0; nj < 4; nj++) {
      int colL = wc * 64 + nj * 16 + fr;
      #pragma unroll
      for (int r = 0; r < 4; r++)
        Ts[(wr * 16 + rl0 + r) * TSTRIDE + colL] = acc[mi][nj][r] + bb[nj];
    }
    __syncthreads();
    #pragma unroll
    for (int i = 0; i < 16; i++) {             // 32*256 f32 / 512 thr
      int flat = i * 512 + tid;
      int rowf = flat >> 8, col = flat & 255;
      float v = Ts[rowf * TSTRIDE + col];
      int row_g = bm * 256 + (rowf >> 4) * 128 + mi * 16 + (rowf & 15);
      int col_g = bn * 256 + col;
      if (col_g < N)
        Cout[(size_t)row_g * ldc + col_g] = v;
    }
    if (mi < 7) __syncthreads();
  }
}

// =============================================================================
extern "C" void kernel_launch(void* const* d_in, const int* in_sizes, int n_in,
                              void* d_out, int out_size, void* d_ws, size_t ws_size,
                              hipStream_t stream) {
  const float* z        = (const float*)d_in[0];
  const int*   ids      = (const int*)d_in[1];
  const float* tok      = (const float*)d_in[2];
  const float* pos      = (const float*)d_in[3];
  const float* lp_w     = (const float*)d_in[4];
  const float* lp_b     = (const float*)d_in[5];
  const float* lp_g     = (const float*)d_in[6];
  const float* lp_be    = (const float*)d_in[7];
  const float* sa_qkv_w = (const float*)d_in[8];
  const float* sa_qkv_b = (const float*)d_in[9];
  const float* sa_out_w = (const float*)d_in[10];
  const float* sa_out_b = (const float*)d_in[11];
  const float* ca_qkv_w = (const float*)d_in[12];
  const float* ca_qkv_b = (const float*)d_in[13];
  const float* ca_out_w = (const float*)d_in[14];
  const float* ca_out_b = (const float*)d_in[15];
  const float* ln1_g    = (const float*)d_in[16];
  const float* ln1_b    = (const float*)d_in[17];
  const float* ln2_g    = (const float*)d_in[18];
  const float* ln2_b    = (const float*)d_in[19];
  const float* ln3_g    = (const float*)d_in[20];
  const float* ln3_b    = (const float*)d_in[21];
  const float* ff1_w    = (const float*)d_in[22];
  const float* ff1_b    = (const float*)d_in[23];
  const float* ff2_w    = (const float*)d_in[24];
  const float* ff2_b    = (const float*)d_in[25];
  const float* op_w     = (const float*)d_in[26];
  const float* op_b     = (const float*)d_in[27];

  char* ws = (char*)d_ws;
  float* X      = (float*)(ws + 0);           // 4096x512 f32
  u16*   Yb     = (u16*)(ws + 8388608);       // 4096x512 bf16
  u16*   QKVb   = (u16*)(ws + 16777216);      // 4096x1536 bf16
  u16*   Xb     = (u16*)(ws + 29360128);      // 4096x512 bf16
  u16*   Ob     = (u16*)(ws + 33554432);      // 4096x512 bf16
  u16*   H1b    = (u16*)(ws + 37748736);      // 4096x2048 bf16
  float* mem    = (float*)(ws + 54525952);    // 32x512 f32
  float* ca_add = (float*)(ws + 54657024);    // 4x32x512 f32
  u16*   Wa     = (u16*)(ws + 55050240);      // weight arena bf16 (contiguous)

  u16* Wqkv = Wa;                              // 4 x 1536x512
  u16* Wout = Wa + 3145728;                    // 4 x 512x512
  u16* Wff1 = Wa + 4194304;                    // 4 x 2048x512
  u16* Wff2 = Wa + 8388608;                    // 4 x 512x2048
  u16* Wop  = Wa + 12582912;                   // 50304x512 (zero-padded tail)

  k_latent_mem<<<Bn, 256, 0, stream>>>(z, lp_w, lp_b, lp_g, lp_be, mem);
  k_ca<<<4 * Bn, 256, 0, stream>>>(mem, ca_qkv_w, ca_qkv_b, ca_out_w, ca_out_b, ca_add);
  k_embed<<<Bn * Ln, 128, 0, stream>>>(ids, tok, pos, X, Xb);
  k_cvt_all<<<2048, 256, 0, stream>>>(sa_qkv_w, sa_out_w, ff1_w, ff2_w, op_w,
                                      (us4*)Wa);

  const int M = Bn * Ln;  // 4096
  for (int i = 0; i < 4; i++) {
    k_gemm_bt<2, 128><<<32 * 12, 256, 0, stream>>>(
        Xb, Wqkv + (size_t)i * 1536 * Dn, sa_qkv_b + i * 1536, QKVb, 32, 1536, Dn, 1536);
    k_attn_m<<<Bn * Hn, 256, 0, stream>>>(QKVb, Ob);
    k_gemm_bt<2, 64><<<32 * 8, 256, 0, stream>>>(
        Ob, Wout + (size_t)i * Dn * Dn, sa_out_b + i * Dn, Yb, 32, Dn, Dn, Dn);
    k_add_ln12<<<M, 128, 0, stream>>>(X, Xb, Yb, ca_add + (size_t)i * Bn * Dn,
                                      ln1_g + i * Dn, ln1_b + i * Dn,
                                      ln2_g + i * Dn, ln2_b + i * Dn);
    k_gemm_bt<1, 128><<<32 * 16, 256, 0, stream>>>(
        Xb, Wff1 + (size_t)i * DFn * Dn, ff1_b + i * DFn, H1b, 32, DFn, Dn, DFn);
    k_gemm_bt<2, 64><<<32 * 8, 256, 0, stream>>>(
        H1b, Wff2 + (size_t)i * Dn * DFn, ff2_b + i * Dn, Yb, 32, Dn, DFn, Dn);
    k_add_ln<<<M, 128, 0, stream>>>(X, Xb, Yb, ln3_g + i * Dn, ln3_b + i * Dn);
  }

  // final vocab projection -> d_out (f32): XCD-chunked grid 8 x (8 bm x 50 bn)
  k_gemm_v256<<<3200, 512, 0, stream>>>(
      Xb, Wop, op_b, (float*)d_out, 16, Vn, Dn, Vn);
}

// Round 13
// 795.597 us; speedup vs baseline: 1.0844x; 1.0409x over previous
//
#include <hip/hip_runtime.h>
#include <math.h>

typedef __attribute__((ext_vector_type(8))) short short8;
typedef __attribute__((ext_vector_type(4))) float f32x4;
typedef __attribute__((ext_vector_type(4))) float f4;
typedef __attribute__((ext_vector_type(4))) unsigned short us4;
typedef unsigned short u16;

#define Bn 32
#define Ln 128
#define Dn 512
#define LATn 256
#define Vn 50257
#define VPAD 50304
#define DFn 2048
#define Hn 8
#define HDn 64

#define GLD(src, dst) __builtin_amdgcn_global_load_lds( \
    (const __attribute__((address_space(1))) unsigned int*)(src), \
    (__attribute__((address_space(3))) unsigned int*)(dst), 16, 0, 0)

__device__ __forceinline__ u16 f2bf(float f) {
  union { float f; unsigned u; } v; v.f = f;
  unsigned r = 0x7FFFu + ((v.u >> 16) & 1u);
  return (u16)((v.u + r) >> 16);
}
__device__ __forceinline__ float bf2f(u16 u) {
  union { unsigned u; float f; } v; v.u = ((unsigned)u) << 16;
  return v.f;
}

// ---------------- all weights f32 -> bf16, one kernel (contiguous dst arena) -
__global__ __launch_bounds__(256)
void k_cvt_all(const float* __restrict__ s0, const float* __restrict__ s1,
               const float* __restrict__ s2, const float* __restrict__ s3,
               const float* __restrict__ s4, us4* __restrict__ dst) {
  const int C0 = 786432;    // qkv  4*1536*512/4
  const int C1 = 1048576;   // +out 4*512*512/4
  const int C2 = 2097152;   // +ff1 4*2048*512/4
  const int C3 = 3145728;   // +ff2
  const int C4 = 9584640;   // +op (VPAD*512/4)
  const int OPN4 = 6432896; // op real Vn*512/4
  int i = blockIdx.x * blockDim.x + threadIdx.x;
  int stride = gridDim.x * blockDim.x;
  for (; i < C4; i += stride) {
    const f4* src; int off; bool valid = true;
    if (i < C0)      { src = (const f4*)s0; off = i; }
    else if (i < C1) { src = (const f4*)s1; off = i - C0; }
    else if (i < C2) { src = (const f4*)s2; off = i - C1; }
    else if (i < C3) { src = (const f4*)s3; off = i - C2; }
    else             { src = (const f4*)s4; off = i - C3; valid = off < OPN4; }
    us4 o;
    if (valid) {
      f4 v = src[off];
      o[0] = f2bf(v[0]); o[1] = f2bf(v[1]); o[2] = f2bf(v[2]); o[3] = f2bf(v[3]);
    } else { o[0] = 0; o[1] = 0; o[2] = 0; o[3] = 0; }
    dst[i] = o;
  }
}

// ---------------- latent_proj: mem = LN(GELU(z @ lp_w.T + lp_b)) -------------
__global__ __launch_bounds__(256)
void k_latent_mem(const float* __restrict__ z, const float* __restrict__ lp_w,
                  const float* __restrict__ lp_b, const float* __restrict__ g,
                  const float* __restrict__ be, float* __restrict__ mem) {
  __shared__ float zs[LATn];
  __shared__ float red[16];
  int b = blockIdx.x, t = threadIdx.x;
  zs[t] = z[b * LATn + t];
  __syncthreads();
  float h[2];
  #pragma unroll
  for (int j = 0; j < 2; j++) {
    int oj = t + j * 256;
    const float* w = lp_w + (size_t)oj * LATn;
    float s0 = 0, s1 = 0, s2 = 0, s3 = 0;
    for (int k = 0; k < LATn; k += 4) {
      s0 += zs[k] * w[k]; s1 += zs[k+1] * w[k+1];
      s2 += zs[k+2] * w[k+2]; s3 += zs[k+3] * w[k+3];
    }
    float x = s0 + s1 + s2 + s3 + lp_b[oj];
    h[j] = 0.5f * x * (1.0f + erff(x * 0.70710678118654752f));
  }
  float sum = h[0] + h[1], sq = h[0]*h[0] + h[1]*h[1];
  for (int off = 32; off; off >>= 1) {
    sum += __shfl_down(sum, off, 64);
    sq  += __shfl_down(sq,  off, 64);
  }
  int lane = t & 63, wid = t >> 6;
  if (!lane) { red[wid] = sum; red[8 + wid] = sq; }
  __syncthreads();
  float ts = red[0] + red[1] + red[2] + red[3];
  float tq = red[8] + red[9] + red[10] + red[11];
  float mu = ts * (1.0f / Dn);
  float var = tq * (1.0f / Dn) - mu * mu;
  float rstd = rsqrtf(fmaxf(var, 0.0f) + 1e-5f);
  #pragma unroll
  for (int j = 0; j < 2; j++) {
    int oj = t + j * 256;
    mem[b * Dn + oj] = (h[j] - mu) * rstd * g[oj] + be[oj];
  }
}

// ------------- cross-attention precompute (Lk=1 => softmax==1 => o = v) ------
__global__ __launch_bounds__(256)
void k_ca(const float* __restrict__ mem, const float* __restrict__ ca_qkv_w,
          const float* __restrict__ ca_qkv_b, const float* __restrict__ ca_out_w,
          const float* __restrict__ ca_out_b, float* __restrict__ ca_add) {
  int blk = blockIdx.x;
  int i = blk >> 5, b = blk & 31, t = threadIdx.x;
  __shared__ float ms[Dn];
  __shared__ float vs[Dn];
  ms[t] = mem[b * Dn + t];
  ms[t + 256] = mem[b * Dn + t + 256];
  __syncthreads();
  const float* wv = ca_qkv_w + ((size_t)i * 1536 + 1024) * Dn;
  const float* bv = ca_qkv_b + i * 1536 + 1024;
  for (int j = t; j < Dn; j += 256) {
    const float* w = wv + (size_t)j * Dn;
    float s0 = 0, s1 = 0, s2 = 0, s3 = 0;
    for (int k = 0; k < Dn; k += 4) {
      s0 += ms[k]*w[k]; s1 += ms[k+1]*w[k+1]; s2 += ms[k+2]*w[k+2]; s3 += ms[k+3]*w[k+3];
    }
    vs[j] = s0 + s1 + s2 + s3 + bv[j];
  }
  __syncthreads();
  const float* wo = ca_out_w + (size_t)i * Dn * Dn;
  const float* bo = ca_out_b + i * Dn;
  for (int j = t; j < Dn; j += 256) {
    const float* w = wo + (size_t)j * Dn;
    float s0 = 0, s1 = 0, s2 = 0, s3 = 0;
    for (int k = 0; k < Dn; k += 4) {
      s0 += vs[k]*w[k]; s1 += vs[k+1]*w[k+1]; s2 += vs[k+2]*w[k+2]; s3 += vs[k+3]*w[k+3];
    }
    ca_add[((size_t)i * Bn + b) * Dn + j] = s0 + s1 + s2 + s3 + bo[j];
  }
}

// ---------------- embedding: Xb = bf16(tok_emb[ids] + pos_emb) ---------------
__global__ __launch_bounds__(128)
void k_embed(const int* __restrict__ ids, const float* __restrict__ tok,
             const float* __restrict__ pos, u16* __restrict__ Xb) {
  int r = blockIdx.x;
  int l = r & (Ln - 1);
  int id = ids[r];
  int c = threadIdx.x * 4;
  f4 te = *(const f4*)&tok[(size_t)id * Dn + c];
  f4 pe = *(const f4*)&pos[(size_t)l * Dn + c];
  f4 v = te + pe;
  us4 o = { f2bf(v[0]), f2bf(v[1]), f2bf(v[2]), f2bf(v[3]) };
  *(us4*)&Xb[(size_t)r * Dn + c] = o;
}

// ---------------- fused residual add + LayerNorm (bf16 residual stream) ------
__global__ __launch_bounds__(128)
void k_add_ln(u16* __restrict__ Xb, const u16* __restrict__ Y,
              const float* __restrict__ g, const float* __restrict__ be) {
  int r = blockIdx.x, t = threadIdx.x;
  int c = t * 4;
  us4 xb = *(const us4*)&Xb[(size_t)r * Dn + c];
  us4 yb = *(const us4*)&Y[(size_t)r * Dn + c];
  f4 v;
  v[0] = bf2f(xb[0]) + bf2f(yb[0]); v[1] = bf2f(xb[1]) + bf2f(yb[1]);
  v[2] = bf2f(xb[2]) + bf2f(yb[2]); v[3] = bf2f(xb[3]) + bf2f(yb[3]);
  float sum = v[0] + v[1] + v[2] + v[3];
  float sq = v[0]*v[0] + v[1]*v[1] + v[2]*v[2] + v[3]*v[3];
  for (int off = 32; off; off >>= 1) {
    sum += __shfl_down(sum, off, 64);
    sq  += __shfl_down(sq,  off, 64);
  }
  __shared__ float red[4];
  int lane = t & 63, w = t >> 6;
  if (!lane) { red[w] = sum; red[2 + w] = sq; }
  __syncthreads();
  sum = red[0] + red[1]; sq = red[2] + red[3];
  float mu = sum * (1.0f / Dn);
  float var = sq * (1.0f / Dn) - mu * mu;
  float rstd = rsqrtf(fmaxf(var, 0.0f) + 1e-5f);
  f4 gg = *(const f4*)&g[c];
  f4 bb = *(const f4*)&be[c];
  f4 o = (v - mu) * rstd * gg + bb;
  us4 ob = { f2bf(o[0]), f2bf(o[1]), f2bf(o[2]), f2bf(o[3]) };
  *(us4*)&Xb[(size_t)r * Dn + c] = ob;
}

// ---------------- fused LN1(X+Y) then LN2(. + CA), bf16 residual -------------
__global__ __launch_bounds__(128)
void k_add_ln12(u16* __restrict__ Xb, const u16* __restrict__ Y,
                const float* __restrict__ CA,
                const float* __restrict__ g1, const float* __restrict__ b1,
                const float* __restrict__ g2, const float* __restrict__ b2) {
  int r = blockIdx.x, t = threadIdx.x;
  int c = t * 4;
  __shared__ float red[8];
  int lane = t & 63, w = t >> 6;
  us4 xb = *(const us4*)&Xb[(size_t)r * Dn + c];
  us4 yb = *(const us4*)&Y[(size_t)r * Dn + c];
  f4 v;
  v[0] = bf2f(xb[0]) + bf2f(yb[0]); v[1] = bf2f(xb[1]) + bf2f(yb[1]);
  v[2] = bf2f(xb[2]) + bf2f(yb[2]); v[3] = bf2f(xb[3]) + bf2f(yb[3]);
  float sum = v[0] + v[1] + v[2] + v[3];
  float sq = v[0]*v[0] + v[1]*v[1] + v[2]*v[2] + v[3]*v[3];
  for (int off = 32; off; off >>= 1) {
    sum += __shfl_down(sum, off, 64);
    sq  += __shfl_down(sq,  off, 64);
  }
  if (!lane) { red[w] = sum; red[2 + w] = sq; }
  __syncthreads();
  sum = red[0] + red[1]; sq = red[2] + red[3];
  float mu = sum * (1.0f / Dn);
  float var = sq * (1.0f / Dn) - mu * mu;
  float rstd = rsqrtf(fmaxf(var, 0.0f) + 1e-5f);
  f4 g1v = *(const f4*)&g1[c];
  f4 b1v = *(const f4*)&b1[c];
  f4 o1 = (v - mu) * rstd * g1v + b1v;
  f4 ca = *(const f4*)&CA[(size_t)(r >> 7) * Dn + c];
  f4 v2 = o1 + ca;
  float sum2 = v2[0] + v2[1] + v2[2] + v2[3];
  float sq2 = v2[0]*v2[0] + v2[1]*v2[1] + v2[2]*v2[2] + v2[3]*v2[3];
  for (int off = 32; off; off >>= 1) {
    sum2 += __shfl_down(sum2, off, 64);
    sq2  += __shfl_down(sq2,  off, 64);
  }
  if (!lane) { red[4 + w] = sum2; red[6 + w] = sq2; }
  __syncthreads();
  sum2 = red[4] + red[5]; sq2 = red[6] + red[7];
  float mu2 = sum2 * (1.0f / Dn);
  float var2 = sq2 * (1.0f / Dn) - mu2 * mu2;
  float rstd2 = rsqrtf(fmaxf(var2, 0.0f) + 1e-5f);
  f4 g2v = *(const f4*)&g2[c];
  f4 b2v = *(const f4*)&b2[c];
  f4 o2 = (v2 - mu2) * rstd2 * g2v + b2v;
  us4 ob = { f2bf(o2[0]), f2bf(o2[1]), f2bf(o2[2]), f2bf(o2[3]) };
  *(us4*)&Xb[(size_t)r * Dn + c] = ob;
}

// ---------------- MFMA causal attention (R9-R12 passing kernel, unchanged) ---
__global__ __launch_bounds__(256, 1)
void k_attn_m(const u16* __restrict__ QKV, u16* __restrict__ Ob) {
  constexpr int QS = 0;
  constexpr int KS = 9216;
  constexpr int SFB = 36864;
  constexpr int VTB = 36864 + 66048;
  constexpr int MXB = VTB + 17408;
  constexpr int LXB = MXB + 1024;
  __shared__ __align__(16) char smem[LXB + 1024];
  u16* U = (u16*)smem;
  float* Sf = (float*)(smem + SFB);
  u16* Vt = (u16*)(smem + VTB);
  float* Mx = (float*)(smem + MXB);
  float* Lx = (float*)(smem + LXB);

  int bh = blockIdx.x, b = bh >> 3, h = bh & 7;
  int tid = threadIdx.x, lane = tid & 63, wid = tid >> 6;
  int r = tid & 127, half = tid >> 7;

  {
    const u16* qk = QKV + (size_t)(b * 128 + r) * 1536 + (half ? 512 : 0) + h * 64;
    u16* dst = U + (half ? KS : QS) + r * 72;
    #pragma unroll
    for (int i = 0; i < 64; i += 8)
      *(short8*)(dst + i) = *(const short8*)(qk + i);
    const u16* vsrc = QKV + (size_t)(b * 128 + r) * 1536 + 1024 + h * 64 + half * 32;
    #pragma unroll
    for (int i = 0; i < 32; i += 8) {
      short8 v = *(const short8*)(vsrc + i);
      #pragma unroll
      for (int j = 0; j < 8; j++)
        Vt[(half * 32 + i + j) * 136 + r] = (u16)v[j];
    }
  }
  __syncthreads();

  int qb = wid * 32;
  int fr = lane & 15, qk8 = (lane >> 4) * 8, qrl = (lane >> 4) * 4;
  f32x4 sacc[2][8] = {};
  #pragma unroll
  for (int s = 0; s < 2; s++) {
    short8 av[2], bv[8];
    #pragma unroll
    for (int mi = 0; mi < 2; mi++)
      av[mi] = *(const short8*)(U + QS + (qb + mi * 16 + fr) * 72 + s * 32 + qk8);
    #pragma unroll
    for (int nj = 0; nj < 8; nj++)
      bv[nj] = *(const short8*)(U + KS + (nj * 16 + fr) * 72 + s * 32 + qk8);
    #pragma unroll
    for (int mi = 0; mi < 2; mi++)
      #pragma unroll
      for (int nj = 0; nj < 8; nj++)
        sacc[mi][nj] = __builtin_amdgcn_mfma_f32_16x16x32_bf16(
            av[mi], bv[nj], sacc[mi][nj], 0, 0, 0);
  }
  #pragma unroll
  for (int mi = 0; mi < 2; mi++)
    #pragma unroll
    for (int nj = 0; nj < 8; nj++)
      #pragma unroll
      for (int g = 0; g < 4; g++) {
        int q = qb + mi * 16 + qrl + g;
        int k = nj * 16 + fr;
        Sf[q * 129 + k] = (k <= q) ? sacc[mi][nj][g] * 0.125f : -1e30f;
      }
  __syncthreads();

  int kr = half * 64;
  float m = -1e30f;
  for (int k = 0; k < 64; k++) m = fmaxf(m, Sf[r * 129 + kr + k]);
  Mx[half * 128 + r] = m;
  __syncthreads();
  float mm = fmaxf(Mx[r], Mx[128 + r]);
  float l = 0.0f;
  for (int k = 0; k < 64; k++) {
    float p = __expf(Sf[r * 129 + kr + k] - mm);
    Sf[r * 129 + kr + k] = p;
    l += p;
  }
  Lx[half * 128 + r] = l;
  __syncthreads();
  float linv = 1.0f / (Lx[r] + Lx[128 + r]);
  #pragma unroll
  for (int kc = 0; kc < 8; kc++) {
    short8 pv;
    #pragma unroll
    for (int j = 0; j < 8; j++)
      pv[j] = (short)f2bf(Sf[r * 129 + kr + kc * 8 + j] * linv);
    *(short8*)(U + r * 136 + kr + kc * 8) = pv;
  }
  __syncthreads();

  f32x4 oacc[2][4] = {};
  #pragma unroll
  for (int ks = 0; ks < 4; ks++) {
    short8 av[2], bv[4];
    #pragma unroll
    for (int mi = 0; mi < 2; mi++)
      av[mi] = *(const short8*)(U + (qb + mi * 16 + fr) * 136 + ks * 32 + qk8);
    #pragma unroll
    for (int nj = 0; nj < 4; nj++)
      bv[nj] = *(const short8*)(Vt + (nj * 16 + fr) * 136 + ks * 32 + qk8);
    #pragma unroll
    for (int mi = 0; mi < 2; mi++)
      #pragma unroll
      for (int nj = 0; nj < 4; nj++)
        oacc[mi][nj] = __builtin_amdgcn_mfma_f32_16x16x32_bf16(
            av[mi], bv[nj], oacc[mi][nj], 0, 0, 0);
  }
  #pragma unroll
  for (int mi = 0; mi < 2; mi++)
    #pragma unroll
    for (int nj = 0; nj < 4; nj++)
      #pragma unroll
      for (int g = 0; g < 4; g++) {
        int q = qb + mi * 16 + qrl + g;
        int d = nj * 16 + fr;
        Ob[(size_t)(b * 128 + q) * 512 + h * 64 + d] = f2bf(oacc[mi][nj][g]);
      }
}

// ---------------- layer GEMM (R8-R12 passing kernel, unchanged) --------------
template <int EPI, int BNT>
__global__ __launch_bounds__(256, (BNT == 128 ? 2 : 3))
void k_gemm_bt(const u16* __restrict__ A, const u16* __restrict__ Bw,
               const float* __restrict__ bias, void* __restrict__ Cout,
               int gm, int N, int K, int ldc) {
  constexpr int NREP = BNT / 32;
  constexpr int ASTRIDE = 128 * 64;
  constexpr int BSTRIDE = BNT * 64;
  constexpr int TSTRIDE = BNT + 4;
  constexpr int NLA = 4;
  constexpr int NLB = BNT / 32;
  __shared__ __align__(16) char smem[(ASTRIDE + BSTRIDE) * 4];
  u16* As = (u16*)smem;
  u16* Bs = (u16*)(smem + ASTRIDE * 4);
  float* Ts = (float*)smem;

  int lin = blockIdx.x;
  int bm = lin % gm, bn = lin / gm;
  int tid = threadIdx.x, lane = tid & 63, wid = tid >> 6;
  int wr = wid >> 1, wc = wid & 1;
  int fr = lane & 15, q = lane >> 4;
  f32x4 acc[4][NREP] = {};

  auto stage = [&](int it) {
    int buf = it & 1;
    #pragma unroll
    for (int l = 0; l < NLA; l++) {
      int c = tid + l * 256;
      int row = c >> 3;
      int kcg = (c & 7) ^ (row & 7);
      GLD(A + (size_t)(bm * 128 + row) * K + it * 64 + kcg * 8,
          (char*)(As + buf * ASTRIDE) + c * 16);
    }
    #pragma unroll
    for (int l = 0; l < NLB; l++) {
      int c = tid + l * 256;
      int row = c >> 3;
      int kcg = (c & 7) ^ (row & 7);
      GLD(Bw + (size_t)(bn * BNT + row) * K + it * 64 + kcg * 8,
          (char*)(Bs + buf * BSTRIDE) + c * 16);
    }
  };

  int nt = K >> 6;
  stage(0);
  for (int it = 0; it < nt; ++it) {
    int cur = it & 1;
    if (it + 1 < nt) {
      stage(it + 1);
      if constexpr (BNT == 128) asm volatile("s_waitcnt vmcnt(8)" ::: "memory");
      else                      asm volatile("s_waitcnt vmcnt(6)" ::: "memory");
    } else {
      asm volatile("s_waitcnt vmcnt(0)" ::: "memory");
    }
    __builtin_amdgcn_sched_barrier(0);
    __builtin_amdgcn_s_barrier();
    __builtin_amdgcn_sched_barrier(0);
    short8 av[2][4], bv[2][NREP];
    #pragma unroll
    for (int s = 0; s < 2; s++) {
      #pragma unroll
      for (int mi = 0; mi < 4; mi++) {
        int row = wr * 64 + mi * 16 + fr;
        int phys = (s * 4 + q) ^ (row & 7);
        av[s][mi] = *(const short8*)&As[cur * ASTRIDE + row * 64 + phys * 8];
      }
      #pragma unroll
      for (int nj = 0; nj < NREP; nj++) {
        int row = wc * (BNT / 2) + nj * 16 + fr;
        int phys = (s * 4 + q) ^ (row & 7);
        bv[s][nj] = *(const short8*)&Bs[cur * BSTRIDE + row * 64 + phys * 8];
      }
    }
    #pragma unroll
    for (int s = 0; s < 2; s++)
      #pragma unroll
      for (int mi = 0; mi < 4; mi++)
        #pragma unroll
        for (int nj = 0; nj < NREP; nj++)
          acc[mi][nj] = __builtin_amdgcn_mfma_f32_16x16x32_bf16(
              av[s][mi], bv[s][nj], acc[mi][nj], 0, 0, 0);
    asm volatile("s_waitcnt lgkmcnt(0)" ::: "memory");
    __builtin_amdgcn_sched_barrier(0);
    __builtin_amdgcn_s_barrier();
    __builtin_amdgcn_sched_barrier(0);
  }

  float bb[NREP];
  #pragma unroll
  for (int nj = 0; nj < NREP; nj++) {
    int cg = bn * BNT + wc * (BNT / 2) + nj * 16 + fr;
    bb[nj] = (cg < N) ? bias[cg] : 0.0f;
  }
  int rl0 = (lane >> 4) * 4;
  #pragma unroll
  for (int mi = 0; mi < 4; mi++) {
    #pragma unroll
    for (int nj = 0; nj < NREP; nj++) {
      int colL = wc * (BNT / 2) + nj * 16 + fr;
      #pragma unroll
      for (int r = 0; r < 4; r++)
        Ts[(wr * 16 + rl0 + r) * TSTRIDE + colL] = acc[mi][nj][r] + bb[nj];
    }
    __syncthreads();
    constexpr int ITERS = (32 * BNT) / 256;
    #pragma unroll
    for (int i = 0; i < ITERS; i++) {
      int flat = i * 256 + tid;
      int rowf = flat / BNT, col = flat % BNT;
      float v = Ts[rowf * TSTRIDE + col];
      int row_g = bm * 128 + (rowf >> 4) * 64 + mi * 16 + (rowf & 15);
      int col_g = bn * BNT + col;
      size_t off = (size_t)row_g * ldc + col_g;
      if (EPI == 0) {
        if (col_g < N) ((float*)Cout)[off] = v;
      } else if (EPI == 1) {
        ((u16*)Cout)[off] = f2bf(fmaxf(v, 0.0f));
      } else {
        ((u16*)Cout)[off] = f2bf(v);
      }
    }
    if (mi < 3) __syncthreads();
  }
}

// ---------------- vocab GEMM: 256x256 tile, BK=64, 8 waves (R10 proven) ------
// Linear bm-fastest mapping (R10-exact; R12's XCD chunking measured neutral —
// B fits the 256 MB L3, so block order doesn't change HBM traffic).
__global__ __launch_bounds__(512, 2)
void k_gemm_v256(const u16* __restrict__ A, const u16* __restrict__ Bw,
                 const float* __restrict__ bias, float* __restrict__ Cout,
                 int gm, int N, int K, int ldc) {
  constexpr int ASTRIDE = 256 * 64;            // u16 per A buffer (32 KB)
  constexpr int BSTRIDE = 256 * 64;            // u16 per B buffer (32 KB)
  constexpr int TSTRIDE = 256 + 4;
  __shared__ __align__(16) char smem[(ASTRIDE + BSTRIDE) * 4];   // 128 KB
  u16* As = (u16*)smem;
  u16* Bs = (u16*)(smem + ASTRIDE * 4);
  float* Ts = (float*)smem;                    // epilogue alias [32][260]

  int lin = blockIdx.x;
  int bm = lin % gm, bn = lin / gm;            // bm fastest
  int tid = threadIdx.x, lane = tid & 63, wid = tid >> 6;  // 8 waves
  int wr = wid >> 2, wc = wid & 3;             // 2 x 4 wave grid (128x64 each)
  int fr = lane & 15, q = lane >> 4;
  f32x4 acc[8][4] = {};

  auto stage = [&](int it) {
    int buf = it & 1;
    #pragma unroll
    for (int l = 0; l < 4; l++) {              // A: 256 rows x 8 chunks / 512
      int c = tid + l * 512;
      int row = c >> 3;
      int kcg = (c & 7) ^ (row & 7);
      GLD(A + (size_t)(bm * 256 + row) * K + it * 64 + kcg * 8,
          (char*)(As + buf * ASTRIDE) + c * 16);
    }
    #pragma unroll
    for (int l = 0; l < 4; l++) {              // B: 256 rows x 8 chunks / 512
      int c = tid + l * 512;
      int row = c >> 3;
      int rowg = bn * 256 + row;
      if (rowg > VPAD - 1) rowg = VPAD - 1;    // clamp to zeroed pad row
      int kcg = (c & 7) ^ (row & 7);
      GLD(Bw + (size_t)rowg * K + it * 64 + kcg * 8,
          (char*)(Bs + buf * BSTRIDE) + c * 16);
    }
  };

  int nt = K >> 6;
  stage(0);
  for (int it = 0; it < nt; ++it) {
    int cur = it & 1;
    if (it + 1 < nt) {
      stage(it + 1);                            // writes buf cur^1 (released)
      asm volatile("s_waitcnt vmcnt(8)" ::: "memory");  // stage(it) landed
    } else {
      asm volatile("s_waitcnt vmcnt(0)" ::: "memory");
    }
    __builtin_amdgcn_sched_barrier(0);
    __builtin_amdgcn_s_barrier();               // buf cur ready for all waves
    __builtin_amdgcn_sched_barrier(0);
    #pragma unroll
    for (int s = 0; s < 2; s++) {
      short8 av[8], bv[4];
      #pragma unroll
      for (int mi = 0; mi < 8; mi++) {
        int row = wr * 128 + mi * 16 + fr;
        int phys = (s * 4 + q) ^ (row & 7);
        av[mi] = *(const short8*)&As[cur * ASTRIDE + row * 64 + phys * 8];
      }
      #pragma unroll
      for (int nj = 0; nj < 4; nj++) {
        int row = wc * 64 + nj * 16 + fr;
        int phys = (s * 4 + q) ^ (row & 7);
        bv[nj] = *(const short8*)&Bs[cur * BSTRIDE + row * 64 + phys * 8];
      }
      #pragma unroll
      for (int mi = 0; mi < 8; mi++)
        #pragma unroll
        for (int nj = 0; nj < 4; nj++)
          acc[mi][nj] = __builtin_amdgcn_mfma_f32_16x16x32_bf16(
              av[mi], bv[nj], acc[mi][nj], 0, 0, 0);
    }
    asm volatile("s_waitcnt lgkmcnt(0)" ::: "memory");  // my reads done
    __builtin_amdgcn_sched_barrier(0);
    __builtin_amdgcn_s_barrier();               // buf cur released for restage
    __builtin_amdgcn_sched_barrier(0);
  }

  // epilogue: per mi, 32 rows x 256 cols slab via LDS -> coalesced f32 stores
  float bb[4];
  #pragma unroll
  for (int nj = 0; nj < 4; nj++) {
    int cg = bn * 256 + wc * 64 + nj * 16 + fr;
    bb[nj] = (cg < N) ? bias[cg] : 0.0f;
  }
  int rl0 = (lane >> 4) * 4;
  #pragma unroll
  for (int mi = 0; mi < 8; mi++) {
    #pragma unroll
    for (int nj = 0; nj < 4; nj++) {
      int colL = wc * 64 + nj * 16 + fr;
      #pragma unroll
      for (int r = 0; r < 4; r++)
        Ts[(wr * 16 + rl0 + r) * TSTRIDE + colL] = acc[mi][nj][r] + bb[nj];
    }
    __syncthreads();
    #pragma unroll
    for (int i = 0; i < 16; i++) {             // 32*256 f32 / 512 thr
      int flat = i * 512 + tid;
      int rowf = flat >> 8, col = flat & 255;
      float v = Ts[rowf * TSTRIDE + col];
      int row_g = bm * 256 + (rowf >> 4) * 128 + mi * 16 + (rowf & 15);
      int col_g = bn * 256 + col;
      if (col_g < N)
        Cout[(size_t)row_g * ldc + col_g] = v;
    }
    if (mi < 7) __syncthreads();
  }
}

// =============================================================================
extern "C" void kernel_launch(void* const* d_in, const int* in_sizes, int n_in,
                              void* d_out, int out_size, void* d_ws, size_t ws_size,
                              hipStream_t stream) {
  const float* z        = (const float*)d_in[0];
  const int*   ids      = (const int*)d_in[1];
  const float* tok      = (const float*)d_in[2];
  const float* pos      = (const float*)d_in[3];
  const float* lp_w     = (const float*)d_in[4];
  const float* lp_b     = (const float*)d_in[5];
  const float* lp_g     = (const float*)d_in[6];
  const float* lp_be    = (const float*)d_in[7];
  const float* sa_qkv_w = (const float*)d_in[8];
  const float* sa_qkv_b = (const float*)d_in[9];
  const float* sa_out_w = (const float*)d_in[10];
  const float* sa_out_b = (const float*)d_in[11];
  const float* ca_qkv_w = (const float*)d_in[12];
  const float* ca_qkv_b = (const float*)d_in[13];
  const float* ca_out_w = (const float*)d_in[14];
  const float* ca_out_b = (const float*)d_in[15];
  const float* ln1_g    = (const float*)d_in[16];
  const float* ln1_b    = (const float*)d_in[17];
  const float* ln2_g    = (const float*)d_in[18];
  const float* ln2_b    = (const float*)d_in[19];
  const float* ln3_g    = (const float*)d_in[20];
  const float* ln3_b    = (const float*)d_in[21];
  const float* ff1_w    = (const float*)d_in[22];
  const float* ff1_b    = (const float*)d_in[23];
  const float* ff2_w    = (const float*)d_in[24];
  const float* ff2_b    = (const float*)d_in[25];
  const float* op_w     = (const float*)d_in[26];
  const float* op_b     = (const float*)d_in[27];

  char* ws = (char*)d_ws;
  u16*   Yb     = (u16*)(ws + 8388608);       // 4096x512 bf16
  u16*   QKVb   = (u16*)(ws + 16777216);      // 4096x1536 bf16
  u16*   Xb     = (u16*)(ws + 29360128);      // 4096x512 bf16 (residual stream)
  u16*   Ob     = (u16*)(ws + 33554432);      // 4096x512 bf16
  u16*   H1b    = (u16*)(ws + 37748736);      // 4096x2048 bf16
  float* mem    = (float*)(ws + 54525952);    // 32x512 f32
  float* ca_add = (float*)(ws + 54657024);    // 4x32x512 f32
  u16*   Wa     = (u16*)(ws + 55050240);      // weight arena bf16 (contiguous)

  u16* Wqkv = Wa;                              // 4 x 1536x512
  u16* Wout = Wa + 3145728;                    // 4 x 512x512
  u16* Wff1 = Wa + 4194304;                    // 4 x 2048x512
  u16* Wff2 = Wa + 8388608;                    // 4 x 512x2048
  u16* Wop  = Wa + 12582912;                   // 50304x512 (zero-padded tail)

  k_latent_mem<<<Bn, 256, 0, stream>>>(z, lp_w, lp_b, lp_g, lp_be, mem);
  k_ca<<<4 * Bn, 256, 0, stream>>>(mem, ca_qkv_w, ca_qkv_b, ca_out_w, ca_out_b, ca_add);
  k_embed<<<Bn * Ln, 128, 0, stream>>>(ids, tok, pos, Xb);
  k_cvt_all<<<2048, 256, 0, stream>>>(sa_qkv_w, sa_out_w, ff1_w, ff2_w, op_w,
                                      (us4*)Wa);

  const int M = Bn * Ln;  // 4096
  for (int i = 0; i < 4; i++) {
    k_gemm_bt<2, 128><<<32 * 12, 256, 0, stream>>>(
        Xb, Wqkv + (size_t)i * 1536 * Dn, sa_qkv_b + i * 1536, QKVb, 32, 1536, Dn, 1536);
    k_attn_m<<<Bn * Hn, 256, 0, stream>>>(QKVb, Ob);
    k_gemm_bt<2, 64><<<32 * 8, 256, 0, stream>>>(
        Ob, Wout + (size_t)i * Dn * Dn, sa_out_b + i * Dn, Yb, 32, Dn, Dn, Dn);
    k_add_ln12<<<M, 128, 0, stream>>>(Xb, Yb, ca_add + (size_t)i * Bn * Dn,
                                      ln1_g + i * Dn, ln1_b + i * Dn,
                                      ln2_g + i * Dn, ln2_b + i * Dn);
    k_gemm_bt<1, 128><<<32 * 16, 256, 0, stream>>>(
        Xb, Wff1 + (size_t)i * DFn * Dn, ff1_b + i * DFn, H1b, 32, DFn, Dn, DFn);
    k_gemm_bt<2, 64><<<32 * 8, 256, 0, stream>>>(
        H1b, Wff2 + (size_t)i * Dn * DFn, ff2_b + i * Dn, Yb, 32, Dn, DFn, Dn);
    k_add_ln<<<M, 128, 0, stream>>>(Xb, Yb, ln3_g + i * Dn, ln3_b + i * Dn);
  }

  // final vocab projection -> d_out (f32): 256x256 tiles, 16 x 197 grid
  k_gemm_v256<<<16 * 197, 512, 0, stream>>>(
      Xb, Wop, op_b, (float*)d_out, 16, Vn, Dn, Vn);
}